// Round 14
// baseline (755.526 us; speedup 1.0000x reference)
//
#include <hip/hip_runtime.h>
#include <hip/hip_bf16.h>

typedef __attribute__((ext_vector_type(8))) short short8;
typedef __attribute__((ext_vector_type(4))) float f32x4;

static __device__ __forceinline__ float b2f(unsigned short u) {
  return __uint_as_float(((unsigned int)u) << 16);
}
static __device__ __forceinline__ unsigned short f2bs(float f) {
  unsigned int u = __float_as_uint(f);
  u = u + 0x7FFFu + ((u >> 16) & 1u);   // RNE (no NaN inputs here)
  return (unsigned short)(u >> 16);
}
// pair f32 -> packed bf16 (HW v_cvt_pk_bf16_f32, RNE)
static __device__ __forceinline__ unsigned int cvt2(float a, float b) {
  __hip_bfloat162 h = __float22bfloat162_rn(make_float2(a, b));
  return *(unsigned int*)&h;
}

// async global->LDS DMA, 16B per lane; LDS dest = wave-uniform base + lane*16
static __device__ __forceinline__ void gload16(const void* g, void* l) {
  __builtin_amdgcn_global_load_lds(
      (const __attribute__((address_space(1))) void*)g,
      (__attribute__((address_space(3))) void*)l, 16, 0, 0);
}

enum { EPI_BF16_SUMSQ = 1, EPI_BF16 = 2, EPI_F32_RESID = 3 };

// ---------------- bf16-A GEMM (m97 structure, proven Round 6) ----------------
// rowscale (raw sumsq): EPI_BF16 -> v = (acc*escale)*rs + bias;
//                       EPI_F32_RESID -> v = acc + bias + rs*resid.
template<int BM, int BN, int EPI, bool XCD1D>
__global__ __launch_bounds__(256, 4) void gemm_bt(
    const short* __restrict__ A, const short* __restrict__ B, void* __restrict__ Cv,
    const float* __restrict__ bias, const unsigned short* __restrict__ residb,
    float* __restrict__ sumsq, const float* __restrict__ rowscale,
    long lda, long ldb, long ldc, int K, float escale,
    long aZ, long bZ, long cZ, int biasZ, int ncolb)
{
  constexpr int BK = 64;
  constexpr int WM = BM / 2, WN = BN / 2, MR = WM / 16, NR = WN / 16;
  __shared__ __align__(16) short As[BM * BK];
  __shared__ __align__(16) short Bs[BN * BK];
  const int t = threadIdx.x;
  const int zb = blockIdx.z;
  long bxc, byp;
  if constexpr (XCD1D) {
    int bid = blockIdx.x;
    int per = gridDim.x >> 3;
    int ppx = per / ncolb;
    int xcd = bid & 7, j = bid >> 3;
    byp = (long)xcd * ppx + j / ncolb;
    bxc = j % ncolb;
  } else {
    byp = blockIdx.x; bxc = blockIdx.y;
  }
  const long row0 = byp * BM;
  const long col0 = bxc * BN;
  const int wave = t >> 6, lane = t & 63;
  const int wr = wave >> 1, wc = wave & 1;
  const int lr = lane & 15, lg = lane >> 4;
  const short* Az = A + (size_t)zb * aZ;
  const short* Bz = B + (size_t)zb * bZ;
  const int lrow8 = lane >> 3;
  const int lgran = (lane & 7) ^ lrow8;

  auto dmaA = [&](int k0) {
    #pragma unroll
    for (int i = 0; i < BM / 32; ++i) {
      int c = wave * (BM / 32) + i;
      gload16(Az + (size_t)(row0 + c * 8 + lrow8) * lda + k0 + lgran * 8,
              &As[c * 512]);
    }
  };
  auto dmaB = [&](int k0) {
    #pragma unroll
    for (int i = 0; i < BN / 32; ++i) {
      int c = wave * (BN / 32) + i;
      gload16(Bz + (size_t)(col0 + c * 8 + lrow8) * ldb + k0 + lgran * 8,
              &Bs[c * 512]);
    }
  };

  const f32x4 zero4 = {0.f, 0.f, 0.f, 0.f};
  f32x4 acc[MR][NR];
  #pragma unroll
  for (int m = 0; m < MR; ++m)
    #pragma unroll
    for (int n = 0; n < NR; ++n) acc[m][n] = zero4;

  dmaA(0); dmaB(0);
  __syncthreads();

  const int nk = K / BK;
  for (int kt = 0; kt < nk; ++kt) {
    #pragma unroll
    for (int kk = 0; kk < 2; ++kk) {
      short8 a[MR], b[NR];
      #pragma unroll
      for (int m = 0; m < MR; ++m) {
        int row = wr * WM + m * 16 + lr, col = kk * 32 + lg * 8;
        a[m] = *(const short8*)&As[row * 64 + (col ^ ((row & 7) << 3))];
      }
      #pragma unroll
      for (int n = 0; n < NR; ++n) {
        int row = wc * WN + n * 16 + lr, col = kk * 32 + lg * 8;
        b[n] = *(const short8*)&Bs[row * 64 + (col ^ ((row & 7) << 3))];
      }
      #pragma unroll
      for (int m = 0; m < MR; ++m)
        #pragma unroll
        for (int n = 0; n < NR; ++n)
          acc[m][n] = __builtin_amdgcn_mfma_f32_16x16x32_bf16(a[m], b[n], acc[m][n], 0, 0, 0);
    }
    if (kt + 1 < nk) {
      __syncthreads();
      dmaA((kt + 1) * BK); dmaB((kt + 1) * BK);
      __syncthreads();
    }
  }

  const float* biasz = bias ? (bias + (size_t)zb * biasZ) : nullptr;
  float* Cf = (float*)Cv;
  unsigned short* Cb = (unsigned short*)Cv;
  #pragma unroll
  for (int m = 0; m < MR; ++m) {
    #pragma unroll
    for (int i = 0; i < 4; ++i) {
      long row = row0 + wr * WM + m * 16 + lg * 4 + i;
      float rs = 1.f;
      if (rowscale) rs = 1.f / (sqrtf(rowscale[row]) + 1e-6f);
      float sq = 0.f;
      #pragma unroll
      for (int n = 0; n < NR; ++n) {
        long col = col0 + wc * WN + n * 16 + lr;
        float v = acc[m][n][i] * escale;
        size_t ci = (size_t)zb * cZ + (size_t)row * ldc + col;
        if constexpr (EPI == EPI_F32_RESID) {
          v += biasz[col] + rs * b2f(residb[(size_t)row * ldc + col]);
          Cf[ci] = v;
        } else if constexpr (EPI == EPI_BF16_SUMSQ) {
          if (biasz) v += biasz[col];
          Cb[ci] = f2bs(v);
          sq += v * v;
        } else {                      // EPI_BF16
          v *= rs;
          if (biasz) v += biasz[col];
          Cb[ci] = f2bs(v);
        }
      }
      if constexpr (EPI == EPI_BF16_SUMSQ) {
        #pragma unroll
        for (int off = 1; off < 16; off <<= 1) sq += __shfl_xor(sq, off);
        if (lr == 0) atomicAdd(&sumsq[row], sq);
      }
    }
  }
}

// -------- f32-A fused GEMM, BM=256/BN=128/BK=32, 4x1 wave split, DUAL:
// blocks [0,nz): z path (XCD1D over nz); blocks [nz,..): x path (linear).
// LDS-traffic-minimized geometry: dup_A=1 (each wave owns 64 rows),
// dup_B=4 but B is bf16 and BK=32 -> reads 64KB + writes 40KB per
// block-K-step vs 144KB for the 128x128x64 tile at the same MFMA volume.
// A: raw f32 via global_load_lds, bf16-converted on fragment read (cvt_pk).
// A involution: granule g of row r at slot g ^ (r&7) (8x16B granules/row).
// B involution: slot = g ^ ((r>>1)&3) -- mixes row-parity bank base so a
// 16-lane fragment read covers all 8 bank-quads (2-way = free).
__global__ __launch_bounds__(256, 2) void gemm_af32_dual(
    const float* __restrict__ A, const short* __restrict__ B,
    unsigned short* __restrict__ C, const float* __restrict__ bias,
    float* __restrict__ sumsq, int K, int ncolb, int nz,
    const float* __restrict__ A2, const short* __restrict__ B2,
    unsigned short* __restrict__ C2, const float* __restrict__ bias2,
    float* __restrict__ sumsq2, int K2)
{
  constexpr int BM = 256, BN = 128, BK = 32, WM = 64, MR = 4, NR = 8;
  __shared__ __align__(16) float Asf[BM * BK];   // 32 KB
  __shared__ __align__(16) short Bs[BN * BK];    // 8 KB
  const int t = threadIdx.x;
  const int bid = blockIdx.x;

  const float* Ap; const short* Bp; unsigned short* Cp;
  const float* biasp; float* ssp; int Kl;
  long bxc, byp;
  if (bid < nz) {              // z path: XCD1D over nz blocks
    int per = nz >> 3;
    int ppx = per / ncolb;
    int xcd = bid & 7, j = bid >> 3;
    byp = (long)xcd * ppx + j / ncolb;
    bxc = j % ncolb;
    Ap = A; Bp = B; Cp = C; biasp = bias; ssp = sumsq; Kl = K;
  } else {                     // x path: linear, 6 col-blocks
    int j = bid - nz;
    byp = j / 6; bxc = j % 6;
    Ap = A2; Bp = B2; Cp = C2; biasp = bias2; ssp = sumsq2; Kl = K2;
  }
  const long row0 = byp * BM;
  const long col0 = bxc * BN;
  const int wave = t >> 6, lane = t & 63;
  const int lr = lane & 15, lg = lane >> 4;
  const int lrow8 = lane >> 3;                     // A: row in 8-row chunk
  const int lgA = (lane & 7) ^ lrow8;              // A src granule (16B=4 f32)
  const int lrowB = lane >> 2;                     // B: row in 16-row chunk
  const int lgB = (lane & 3) ^ ((lane >> 3) & 3);  // B src granule (16B=8 bf16)

  auto dmaAf = [&](int k0) {
    #pragma unroll
    for (int i = 0; i < 8; ++i) {
      int c = wave * 8 + i;              // 8-row chunk (1KB); row = c*8+lrow8
      gload16(Ap + (size_t)(row0 + c * 8 + lrow8) * Kl + k0 + lgA * 4,
              &Asf[c * 256]);
    }
  };
  auto dmaB = [&](int k0) {
    #pragma unroll
    for (int i = 0; i < 2; ++i) {
      int c = wave * 2 + i;              // 16-row chunk (1KB); row = c*16+lrowB
      gload16(Bp + (size_t)(col0 + c * 16 + lrowB) * Kl + k0 + lgB * 8,
              &Bs[c * 512]);
    }
  };

  const f32x4 zero4 = {0.f, 0.f, 0.f, 0.f};
  f32x4 acc[MR][NR];
  #pragma unroll
  for (int m = 0; m < MR; ++m)
    #pragma unroll
    for (int n = 0; n < NR; ++n) acc[m][n] = zero4;

  dmaAf(0); dmaB(0);
  __syncthreads();

  const int nk = Kl / BK;
  for (int kt = 0; kt < nk; ++kt) {
    short8 a[MR], b[NR];
    #pragma unroll
    for (int m = 0; m < MR; ++m) {
      int row = wave * WM + m * 16 + lr;   // row & 7 == lr & 7
      int j0 = lg * 2;                     // f32 granule pair for this frag
      float4 lo = *(const float4*)&Asf[row * 32 + ((j0 ^ (lr & 7)) << 2)];
      float4 hi = *(const float4*)&Asf[row * 32 + (((j0 + 1) ^ (lr & 7)) << 2)];
      union { short8 s; unsigned int u[4]; } U;
      U.u[0] = cvt2(lo.x, lo.y); U.u[1] = cvt2(lo.z, lo.w);
      U.u[2] = cvt2(hi.x, hi.y); U.u[3] = cvt2(hi.z, hi.w);
      a[m] = U.s;
    }
    #pragma unroll
    for (int n = 0; n < NR; ++n) {
      int row = n * 16 + lr;               // (row>>1)&3 == (lr>>1)&3
      b[n] = *(const short8*)&Bs[row * 32 + ((lg ^ ((lr >> 1) & 3)) << 3)];
    }
    #pragma unroll
    for (int m = 0; m < MR; ++m)
      #pragma unroll
      for (int n = 0; n < NR; ++n)
        acc[m][n] = __builtin_amdgcn_mfma_f32_16x16x32_bf16(a[m], b[n], acc[m][n], 0, 0, 0);
    if (kt + 1 < nk) {
      __syncthreads();
      dmaAf((kt + 1) * BK); dmaB((kt + 1) * BK);
      __syncthreads();
    }
  }

  #pragma unroll
  for (int m = 0; m < MR; ++m) {
    #pragma unroll
    for (int i = 0; i < 4; ++i) {
      long row = row0 + wave * WM + m * 16 + lg * 4 + i;
      float sq = 0.f;
      #pragma unroll
      for (int n = 0; n < NR; ++n) {
        long col = col0 + n * 16 + lr;
        float v = acc[m][n][i] + biasp[col];
        Cp[(size_t)row * 768 + col] = f2bs(v);
        sq += v * v;
      }
      #pragma unroll
      for (int off = 1; off < 16; off <<= 1) sq += __shfl_xor(sq, off);
      if (lr == 0) atomicAdd(&ssp[row], sq);
    }
  }
}

// all weight conversions in one dispatch
__global__ __launch_bounds__(256) void wconv_kernel(
    const float* __restrict__ Wx, const float* __restrict__ Wy,
    const float* __restrict__ ipw, const float* __restrict__ Wo,
    unsigned short* __restrict__ dWx, unsigned short* __restrict__ dWy,
    unsigned short* __restrict__ dWq, unsigned short* __restrict__ dWkT,
    unsigned short* __restrict__ dWv, unsigned short* __restrict__ dWo)
{
  long i = (long)blockIdx.x * 256 + threadIdx.x;
  if (i < 1179648) { dWx[i] = f2bs(Wx[i]); return; }
  i -= 1179648;
  if (i < 786432) { dWy[i] = f2bs(Wy[i]); return; }
  i -= 786432;
  if (i < 589824) { dWq[i] = f2bs(ipw[i]); return; }
  i -= 589824;
  if (i < 589824) {  // WkT[h][n][j] = Wk[h*64+j][n]
    int h = (int)(i / 49152), r = (int)(i % 49152);
    int nn = r >> 6, j = r & 63;
    dWkT[i] = f2bs(ipw[(size_t)(768 + h * 64 + j) * 768 + nn]);
    return;
  }
  i -= 589824;
  if (i < 589824) { dWv[i] = f2bs(ipw[2 * 589824 + i]); return; }
  i -= 589824;
  if (i < 589824) { dWo[i] = f2bs(Wo[i]); }
}

// Per-token fused: S = (qk . z)*invn -> softmax_w -> a = attn*invn -> u = a @ z
__global__ __launch_bounds__(256) void attn_kernel(
    const unsigned short* __restrict__ z, const unsigned short* __restrict__ qk,
    const float* __restrict__ ssy, unsigned short* __restrict__ u)
{
  __shared__ __align__(16) unsigned short zl[16 * 768];
  __shared__ __align__(16) unsigned short ql[12 * 768];
  __shared__ float sc[3][256];
  __shared__ float al[256];
  __shared__ float il[16];
  const int t = threadIdx.x;
  const long m = blockIdx.x;
  const int wv = t >> 6, lane = t & 63;
  const int lr = lane & 15, lg = lane >> 4;

  for (int s = t; s < 1536; s += 256) {
    int row = s / 96, g = s % 96;
    *(short8*)&zl[row * 768 + ((g ^ (row & 7)) << 3)] =
        *(const short8*)(z + m * 12288 + (size_t)s * 8);
  }
  for (int s = t; s < 1152; s += 256) {
    int row = s / 96, g = s % 96;
    *(short8*)&ql[row * 768 + ((g ^ (row & 7)) << 3)] =
        *(const short8*)(qk + m * 9216 + (size_t)s * 8);
  }
  if (t < 16) il[t] = 1.f / (sqrtf(ssy[m * 16 + t]) + 1e-6f);
  __syncthreads();

  f32x4 c = {0.f, 0.f, 0.f, 0.f};
  #pragma unroll
  for (int i = 0; i < 6; ++i) {
    int gb = wv * 24 + i * 4 + lg;
    short8 a = (lr < 12) ? *(const short8*)&ql[lr * 768 + ((gb ^ (lr & 7)) << 3)]
                         : short8{0, 0, 0, 0, 0, 0, 0, 0};
    short8 b = *(const short8*)&zl[lr * 768 + ((gb ^ (lr & 7)) << 3)];
    c = __builtin_amdgcn_mfma_f32_16x16x32_bf16(a, b, c, 0, 0, 0);
  }
  if (wv > 0) {
    #pragma unroll
    for (int i = 0; i < 4; ++i) sc[wv - 1][(lg * 4 + i) * 16 + lr] = c[i];
  }
  __syncthreads();
  if (wv == 0) {
    #pragma unroll
    for (int i = 0; i < 4; ++i) {
      int idx = (lg * 4 + i) * 16 + lr;
      float s = (c[i] + sc[0][idx] + sc[1][idx] + sc[2][idx]) * il[lr];
      float mx = s;
      #pragma unroll
      for (int off = 1; off < 16; off <<= 1) mx = fmaxf(mx, __shfl_xor(mx, off));
      float e = __expf(s - mx);
      float sum = e;
      #pragma unroll
      for (int off = 1; off < 16; off <<= 1) sum += __shfl_xor(sum, off);
      al[idx] = e / sum * il[lr];
    }
  }
  __syncthreads();

  for (int s = t; s < 1152; s += 256) {
    int h = s / 96, gd = s % 96;
    float acc[8] = {0.f, 0.f, 0.f, 0.f, 0.f, 0.f, 0.f, 0.f};
    #pragma unroll
    for (int w = 0; w < 16; ++w) {
      float aw = al[h * 16 + w];
      short8 zz = *(const short8*)&zl[w * 768 + ((gd ^ (w & 7)) << 3)];
      #pragma unroll
      for (int j = 0; j < 8; ++j) acc[j] += aw * b2f((unsigned short)zz[j]);
    }
    short8 o;
    #pragma unroll
    for (int j = 0; j < 8; ++j) o[j] = (short)f2bs(acc[j]);
    *(short8*)&u[m * 9216 + (size_t)s * 8] = o;
  }
}

__global__ __launch_bounds__(256) void ln_kernel(const float* __restrict__ R,
                                                 const float* __restrict__ w,
                                                 const float* __restrict__ b,
                                                 float* __restrict__ out) {
  const long row = blockIdx.x;
  const int t = threadIdx.x;
  const float* rr = R + row * 768;
  float v0 = rr[t], v1 = rr[t + 256], v2 = rr[t + 512];
  float s = v0 + v1 + v2;
  #pragma unroll
  for (int off = 1; off < 64; off <<= 1) s += __shfl_xor(s, off);
  __shared__ float ps[4];
  __shared__ float ps2[4];
  const int wave = t >> 6, lane = t & 63;
  if (lane == 0) ps[wave] = s;
  __syncthreads();
  const float mean = (ps[0] + ps[1] + ps[2] + ps[3]) * (1.f / 768.f);
  const float d0 = v0 - mean, d1 = v1 - mean, d2 = v2 - mean;
  float q = d0 * d0 + d1 * d1 + d2 * d2;
  #pragma unroll
  for (int off = 1; off < 64; off <<= 1) q += __shfl_xor(q, off);
  if (lane == 0) ps2[wave] = q;
  __syncthreads();
  const float var = (ps2[0] + ps2[1] + ps2[2] + ps2[3]) * (1.f / 768.f);
  const float rs = rsqrtf(var + 1e-6f);
  float* oo = out + row * 768;
  oo[t]       = d0 * rs * w[t]       + b[t];
  oo[t + 256] = d1 * rs * w[t + 256] + b[t + 256];
  oo[t + 512] = d2 * rs * w[t + 512] + b[t + 512];
}

extern "C" void kernel_launch(void* const* d_in, const int* in_sizes, int n_in,
                              void* d_out, int out_size, void* d_ws, size_t ws_size,
                              hipStream_t stream) {
  const float* x   = (const float*)d_in[0];   // (8,1024,1536)
  const float* y   = (const float*)d_in[1];   // (8,16384,1024)
  const float* Wx  = (const float*)d_in[2];   // (768,1536)
  const float* bx  = (const float*)d_in[3];
  const float* Wy  = (const float*)d_in[4];   // (768,1024)
  const float* by  = (const float*)d_in[5];
  const float* ipw = (const float*)d_in[6];   // (2304,768)
  const float* ipb = (const float*)d_in[7];
  const float* Wo  = (const float*)d_in[8];   // (768,768)
  const float* ob  = (const float*)d_in[9];
  const float* lnw = (const float*)d_in[10];
  const float* lnb = (const float*)d_in[11];
  float* out = (float*)d_out;

  char* ws = (char*)d_ws;
  size_t off = 0;
  auto alloc = [&](size_t bytes) {
    void* p = ws + off;
    off += (bytes + 4095) & ~(size_t)4095;
    return p;
  };
  unsigned short* Wx_b  = (unsigned short*)alloc(768L * 1536 * 2);
  unsigned short* Wy_b  = (unsigned short*)alloc(768L * 1024 * 2);
  unsigned short* Wq_b  = (unsigned short*)alloc(768L * 768 * 2);
  unsigned short* WkT_b = (unsigned short*)alloc(768L * 768 * 2);
  unsigned short* Wv_b  = (unsigned short*)alloc(768L * 768 * 2);
  unsigned short* Wo_b  = (unsigned short*)alloc(768L * 768 * 2);
  float* ssx = (float*)alloc(8192L * 4);
  float* ssy = (float*)alloc(131072L * 4);
  unsigned short* z_b  = (unsigned short*)alloc(131072L * 768 * 2);
  unsigned short* xq_b = (unsigned short*)alloc(8192L * 768 * 2);
  char* reg = (char*)alloc(134217728L * 2);    // 256 MB scratch region
  unsigned short* q_b  = (unsigned short*)(reg + 25165824);       // 12.6 MB
  unsigned short* qk_b = (unsigned short*)(reg + 37748736);       // 151 MB (also u)
  unsigned short* o_b  = (unsigned short*)(reg + 188743680);      // 12.6 MB
  float*          r_f  = (float*)(reg + 201326592);               // 25.2 MB
  (void)ws_size; (void)in_sizes; (void)n_in; (void)out_size;

  hipMemsetAsync(ssx, 0, 8192L * 4, stream);
  hipMemsetAsync(ssy, 0, 131072L * 4, stream);

  // all weights -> bf16 in one dispatch (4325376 elems)
  wconv_kernel<<<16896, 256, 0, stream>>>(Wx, Wy, ipw, Wo,
                                          Wx_b, Wy_b, Wq_b, WkT_b, Wv_b, Wo_b);

  // merged dispatch: blocks [0,3072) z = y@Wy^T+by (XCD1D, 256-row panels);
  //                  blocks [3072,3264) xq_raw = x@Wx^T+bx. Both + row sumsq.
  gemm_af32_dual<<<3264, 256, 0, stream>>>(
      y, (const short*)Wy_b, z_b, by, ssy, 1024, 6, 3072,
      x, (const short*)Wx_b, xq_b, bx, ssx, 1536);

  // q = rs[m]*(xq_raw @ Wq^T) + bq   (rowscale folded into epilogue), BM=64
  gemm_bt<64, 128, EPI_BF16, false><<<dim3(128, 6, 1), 256, 0, stream>>>(
      (const short*)xq_b, (const short*)Wq_b, q_b, ipb, nullptr, nullptr, ssx,
      768, 768, 768, 768, 1.f, 0, 0, 0, 0, 0);

  // qk[m,h,:] = scale * q[m,h*64:+64] @ WkT[h]   (bk dropped: softmax-invariant)
  gemm_bt<128, 128, EPI_BF16, false><<<dim3(64, 6, 12), 256, 0, stream>>>(
      (const short*)q_b, (const short*)WkT_b, qk_b, nullptr, nullptr, nullptr, nullptr,
      768, 64, 9216, 64, 0.125f, 64, 49152, 768, 0, 0);

  // fused scores/softmax/u  (u overwrites qk slice per token)
  attn_kernel<<<8192, 256, 0, stream>>>(z_b, qk_b, ssy, qk_b);

  // o[:,h*64:+64] = u[:,h,:] @ Wv_h^T + bv_h
  gemm_bt<128, 64, EPI_BF16, false><<<dim3(64, 1, 12), 256, 0, stream>>>(
      (const short*)qk_b, (const short*)Wv_b, o_b, ipb + 1536, nullptr, nullptr, nullptr,
      9216, 768, 768, 768, 1.f, 768, 49152, 64, 64, 0);

  // r = o @ out_w^T + out_b + rs[m]*xq_raw   (residual row-scale), BM=64
  gemm_bt<64, 128, EPI_F32_RESID, false><<<dim3(128, 6, 1), 256, 0, stream>>>(
      (const short*)o_b, (const short*)Wo_b, r_f, ob, xq_b, nullptr, ssx,
      768, 768, 768, 768, 1.f, 0, 0, 0, 0, 0);

  ln_kernel<<<8192, 256, 0, stream>>>(r_f, lnw, lnb, out);
}

// Round 15
// 665.250 us; speedup vs baseline: 1.1357x; 1.1357x over previous
//
#include <hip/hip_runtime.h>
#include <hip/hip_bf16.h>

typedef __attribute__((ext_vector_type(8))) short short8;
typedef __attribute__((ext_vector_type(4))) float f32x4;

static __device__ __forceinline__ float b2f(unsigned short u) {
  return __uint_as_float(((unsigned int)u) << 16);
}
static __device__ __forceinline__ unsigned short f2bs(float f) {
  unsigned int u = __float_as_uint(f);
  u = u + 0x7FFFu + ((u >> 16) & 1u);   // RNE (no NaN inputs here)
  return (unsigned short)(u >> 16);
}
// pair f32 -> packed bf16 (HW v_cvt_pk_bf16_f32, RNE)
static __device__ __forceinline__ unsigned int cvt2(float a, float b) {
  __hip_bfloat162 h = __float22bfloat162_rn(make_float2(a, b));
  return *(unsigned int*)&h;
}

// async global->LDS DMA, 16B per lane; LDS dest = wave-uniform base + lane*16
static __device__ __forceinline__ void gload16(const void* g, void* l) {
  __builtin_amdgcn_global_load_lds(
      (const __attribute__((address_space(1))) void*)g,
      (__attribute__((address_space(3))) void*)l, 16, 0, 0);
}

enum { EPI_BF16_SUMSQ = 1, EPI_BF16 = 2, EPI_F32_RESID = 3 };

// ---------------- bf16-A GEMM (m97 structure, proven Round 6) ----------------
// rowscale (raw sumsq): EPI_BF16 -> v = (acc*escale)*rs + bias;
//                       EPI_F32_RESID -> v = acc + bias + rs*resid.
template<int BM, int BN, int EPI, bool XCD1D>
__global__ __launch_bounds__(256, 4) void gemm_bt(
    const short* __restrict__ A, const short* __restrict__ B, void* __restrict__ Cv,
    const float* __restrict__ bias, const unsigned short* __restrict__ residb,
    float* __restrict__ sumsq, const float* __restrict__ rowscale,
    long lda, long ldb, long ldc, int K, float escale,
    long aZ, long bZ, long cZ, int biasZ, int ncolb)
{
  constexpr int BK = 64;
  constexpr int WM = BM / 2, WN = BN / 2, MR = WM / 16, NR = WN / 16;
  __shared__ __align__(16) short As[BM * BK];
  __shared__ __align__(16) short Bs[BN * BK];
  const int t = threadIdx.x;
  const int zb = blockIdx.z;
  long bxc, byp;
  if constexpr (XCD1D) {
    int bid = blockIdx.x;
    int per = gridDim.x >> 3;
    int ppx = per / ncolb;
    int xcd = bid & 7, j = bid >> 3;
    byp = (long)xcd * ppx + j / ncolb;
    bxc = j % ncolb;
  } else {
    byp = blockIdx.x; bxc = blockIdx.y;
  }
  const long row0 = byp * BM;
  const long col0 = bxc * BN;
  const int wave = t >> 6, lane = t & 63;
  const int wr = wave >> 1, wc = wave & 1;
  const int lr = lane & 15, lg = lane >> 4;
  const short* Az = A + (size_t)zb * aZ;
  const short* Bz = B + (size_t)zb * bZ;
  const int lrow8 = lane >> 3;
  const int lgran = (lane & 7) ^ lrow8;

  auto dmaA = [&](int k0) {
    #pragma unroll
    for (int i = 0; i < BM / 32; ++i) {
      int c = wave * (BM / 32) + i;
      gload16(Az + (size_t)(row0 + c * 8 + lrow8) * lda + k0 + lgran * 8,
              &As[c * 512]);
    }
  };
  auto dmaB = [&](int k0) {
    #pragma unroll
    for (int i = 0; i < BN / 32; ++i) {
      int c = wave * (BN / 32) + i;
      gload16(Bz + (size_t)(col0 + c * 8 + lrow8) * ldb + k0 + lgran * 8,
              &Bs[c * 512]);
    }
  };

  const f32x4 zero4 = {0.f, 0.f, 0.f, 0.f};
  f32x4 acc[MR][NR];
  #pragma unroll
  for (int m = 0; m < MR; ++m)
    #pragma unroll
    for (int n = 0; n < NR; ++n) acc[m][n] = zero4;

  dmaA(0); dmaB(0);
  __syncthreads();

  const int nk = K / BK;
  for (int kt = 0; kt < nk; ++kt) {
    #pragma unroll
    for (int kk = 0; kk < 2; ++kk) {
      short8 a[MR], b[NR];
      #pragma unroll
      for (int m = 0; m < MR; ++m) {
        int row = wr * WM + m * 16 + lr, col = kk * 32 + lg * 8;
        a[m] = *(const short8*)&As[row * 64 + (col ^ ((row & 7) << 3))];
      }
      #pragma unroll
      for (int n = 0; n < NR; ++n) {
        int row = wc * WN + n * 16 + lr, col = kk * 32 + lg * 8;
        b[n] = *(const short8*)&Bs[row * 64 + (col ^ ((row & 7) << 3))];
      }
      #pragma unroll
      for (int m = 0; m < MR; ++m)
        #pragma unroll
        for (int n = 0; n < NR; ++n)
          acc[m][n] = __builtin_amdgcn_mfma_f32_16x16x32_bf16(a[m], b[n], acc[m][n], 0, 0, 0);
    }
    if (kt + 1 < nk) {
      __syncthreads();
      dmaA((kt + 1) * BK); dmaB((kt + 1) * BK);
      __syncthreads();
    }
  }

  const float* biasz = bias ? (bias + (size_t)zb * biasZ) : nullptr;
  float* Cf = (float*)Cv;
  unsigned short* Cb = (unsigned short*)Cv;
  #pragma unroll
  for (int m = 0; m < MR; ++m) {
    #pragma unroll
    for (int i = 0; i < 4; ++i) {
      long row = row0 + wr * WM + m * 16 + lg * 4 + i;
      float rs = 1.f;
      if (rowscale) rs = 1.f / (sqrtf(rowscale[row]) + 1e-6f);
      float sq = 0.f;
      #pragma unroll
      for (int n = 0; n < NR; ++n) {
        long col = col0 + wc * WN + n * 16 + lr;
        float v = acc[m][n][i] * escale;
        size_t ci = (size_t)zb * cZ + (size_t)row * ldc + col;
        if constexpr (EPI == EPI_F32_RESID) {
          v += biasz[col] + rs * b2f(residb[(size_t)row * ldc + col]);
          Cf[ci] = v;
        } else if constexpr (EPI == EPI_BF16_SUMSQ) {
          if (biasz) v += biasz[col];
          Cb[ci] = f2bs(v);
          sq += v * v;
        } else {                      // EPI_BF16
          v *= rs;
          if (biasz) v += biasz[col];
          Cb[ci] = f2bs(v);
        }
      }
      if constexpr (EPI == EPI_BF16_SUMSQ) {
        #pragma unroll
        for (int off = 1; off < 16; off <<= 1) sq += __shfl_xor(sq, off);
        if (lr == 0) atomicAdd(&sumsq[row], sq);
      }
    }
  }
}

// -------- f32-A fused GEMM (Round-8 structure, 4x1 WAVE SPLIT), DUAL dispatch:
// blocks [0,nz): z path (XCD1D mapping over nz blocks);
// blocks [nz,..): x path (linear, 6 col-blocks). Same structure both.
// 4x1 split: wave w owns rows [32w,32w+32) x all 128 cols (MR=2,NR=8) ->
// A-frag LDS reads and cvt_pk HALVED vs 2x2 (no duplicate A work per row-pair).
// A staged raw f32 via global_load_lds, bf16-converted on fragment read.
// Full-rank granule involution: slot g ^ (r&15) -> conflict-free b128 reads.
__global__ __launch_bounds__(256, 3) void gemm_af32_dual(
    const float* __restrict__ A, const short* __restrict__ B,
    unsigned short* __restrict__ C, const float* __restrict__ bias,
    float* __restrict__ sumsq, int K, int ncolb, int nz,
    const float* __restrict__ A2, const short* __restrict__ B2,
    unsigned short* __restrict__ C2, const float* __restrict__ bias2,
    float* __restrict__ sumsq2, int K2)
{
  constexpr int BM = 128, BN = 128, BK = 64, WM = 32, MR = 2, NR = 8;
  __shared__ __align__(16) float Asf[BM * BK];
  __shared__ __align__(16) short Bs[BN * BK];
  const int t = threadIdx.x;
  const int bid = blockIdx.x;

  const float* Ap; const short* Bp; unsigned short* Cp;
  const float* biasp; float* ssp; int Kl;
  long bxc, byp;
  if (bid < nz) {              // z path: XCD1D over nz blocks
    int per = nz >> 3;
    int ppx = per / ncolb;
    int xcd = bid & 7, j = bid >> 3;
    byp = (long)xcd * ppx + j / ncolb;
    bxc = j % ncolb;
    Ap = A; Bp = B; Cp = C; biasp = bias; ssp = sumsq; Kl = K;
  } else {                     // x path: linear, 6 col-blocks
    int j = bid - nz;
    byp = j / 6; bxc = j % 6;
    Ap = A2; Bp = B2; Cp = C2; biasp = bias2; ssp = sumsq2; Kl = K2;
  }
  const long row0 = byp * BM;
  const long col0 = bxc * BN;
  const int wave = t >> 6, lane = t & 63;
  const int lr = lane & 15, lg = lane >> 4;
  const int lrow8 = lane >> 3;
  const int lgran8 = (lane & 7) ^ lrow8;   // B-side (bf16) swizzle
  const int lrow4 = lane >> 4;             // A-side f32: 4 rows per 1KB chunk

  auto dmaAf = [&](int k0) {
    #pragma unroll
    for (int i = 0; i < BM / 16; ++i) {
      int c = wave * (BM / 16) + i;      // 4-row chunk; row = c*4 + lrow4
      // source granule = (lane&15) ^ (row&15); c&3 == i&3 (wave*8 ≡ 0 mod 4)
      int lg16 = (lane & 15) ^ lrow4 ^ ((i & 3) << 2);
      gload16(Ap + (size_t)(row0 + c * 4 + lrow4) * Kl + k0 + lg16 * 4,
              &Asf[c * 256]);
    }
  };
  auto dmaB = [&](int k0) {
    #pragma unroll
    for (int i = 0; i < 4; ++i) {
      int c = wave * 4 + i;              // 8-row chunk
      gload16(Bp + (size_t)(col0 + c * 8 + lrow8) * Kl + k0 + lgran8 * 8,
              &Bs[c * 512]);
    }
  };

  const f32x4 zero4 = {0.f, 0.f, 0.f, 0.f};
  f32x4 acc[MR][NR];
  #pragma unroll
  for (int m = 0; m < MR; ++m)
    #pragma unroll
    for (int n = 0; n < NR; ++n) acc[m][n] = zero4;

  dmaAf(0); dmaB(0);
  __syncthreads();

  const int nk = Kl / BK;
  for (int kt = 0; kt < nk; ++kt) {
    #pragma unroll
    for (int kk = 0; kk < 2; ++kk) {
      short8 a[MR], b[NR];
      #pragma unroll
      for (int m = 0; m < MR; ++m) {
        int row = wave * WM + m * 16 + lr;  // row & 15 == lr
        int j0 = kk * 8 + lg * 2;           // f32 16B-granule index (2 per frag)
        float4 lo = *(const float4*)&Asf[row * 64 + ((j0 ^ lr) << 2)];
        float4 hi = *(const float4*)&Asf[row * 64 + (((j0 + 1) ^ lr) << 2)];
        union { short8 s; unsigned int u[4]; } U;
        U.u[0] = cvt2(lo.x, lo.y); U.u[1] = cvt2(lo.z, lo.w);
        U.u[2] = cvt2(hi.x, hi.y); U.u[3] = cvt2(hi.z, hi.w);
        a[m] = U.s;
      }
      #pragma unroll
      for (int n = 0; n < NR; ++n) {
        int row = n * 16 + lr, col = kk * 32 + lg * 8;
        b[n] = *(const short8*)&Bs[row * 64 + (col ^ ((row & 7) << 3))];
      }
      #pragma unroll
      for (int m = 0; m < MR; ++m)
        #pragma unroll
        for (int n = 0; n < NR; ++n)
          acc[m][n] = __builtin_amdgcn_mfma_f32_16x16x32_bf16(a[m], b[n], acc[m][n], 0, 0, 0);
    }
    if (kt + 1 < nk) {
      __syncthreads();
      dmaAf((kt + 1) * BK); dmaB((kt + 1) * BK);
      __syncthreads();
    }
  }

  #pragma unroll
  for (int m = 0; m < MR; ++m) {
    #pragma unroll
    for (int i = 0; i < 4; ++i) {
      long row = row0 + wave * WM + m * 16 + lg * 4 + i;
      float sq = 0.f;
      #pragma unroll
      for (int n = 0; n < NR; ++n) {
        long col = col0 + n * 16 + lr;
        float v = acc[m][n][i] + biasp[col];
        Cp[(size_t)row * 768 + col] = f2bs(v);
        sq += v * v;
      }
      #pragma unroll
      for (int off = 1; off < 16; off <<= 1) sq += __shfl_xor(sq, off);
      if (lr == 0) atomicAdd(&ssp[row], sq);
    }
  }
}

// all weight conversions in one dispatch; linear parts vectorized (f32x4->short4)
__global__ __launch_bounds__(256) void wconv_kernel(
    const float* __restrict__ Wx, const float* __restrict__ Wy,
    const float* __restrict__ ipw, const float* __restrict__ Wo,
    unsigned short* __restrict__ dWx, unsigned short* __restrict__ dWy,
    unsigned short* __restrict__ dWq, unsigned short* __restrict__ dWkT,
    unsigned short* __restrict__ dWv, unsigned short* __restrict__ dWo)
{
  long i = (long)blockIdx.x * 256 + threadIdx.x;
  if (i < 933888) {            // 4-elem vectorized linear conversions
    const float* s; unsigned short* d; long base = i;
    if (base < 294912) { s = Wx; d = dWx; }
    else if ((base -= 294912) < 196608) { s = Wy; d = dWy; }
    else if ((base -= 196608) < 147456) { s = ipw; d = dWq; }
    else if ((base -= 147456) < 147456) { s = ipw + 2 * 589824; d = dWv; }
    else { base -= 147456; s = Wo; d = dWo; }
    float4 v = ((const float4*)s)[base];
    short4 o;
    o.x = (short)f2bs(v.x); o.y = (short)f2bs(v.y);
    o.z = (short)f2bs(v.z); o.w = (short)f2bs(v.w);
    ((short4*)d)[base] = o;
    return;
  }
  i -= 933888;
  if (i < 589824) {            // WkT[h][n][j] = Wk[h*64+j][n] (gather)
    int h = (int)(i / 49152), r = (int)(i % 49152);
    int nn = r >> 6, j = r & 63;
    dWkT[i] = f2bs(ipw[(size_t)(768 + h * 64 + j) * 768 + nn]);
  }
}

// Per-token fused: S = (qk . z)*invn -> softmax_w -> a = attn*invn -> u = a @ z
__global__ __launch_bounds__(256) void attn_kernel(
    const unsigned short* __restrict__ z, const unsigned short* __restrict__ qk,
    const float* __restrict__ ssy, unsigned short* __restrict__ u)
{
  __shared__ __align__(16) unsigned short zl[16 * 768];
  __shared__ __align__(16) unsigned short ql[12 * 768];
  __shared__ float sc[3][256];
  __shared__ float al[256];
  __shared__ float il[16];
  const int t = threadIdx.x;
  const long m = blockIdx.x;
  const int wv = t >> 6, lane = t & 63;
  const int lr = lane & 15, lg = lane >> 4;

  for (int s = t; s < 1536; s += 256) {
    int row = s / 96, g = s % 96;
    *(short8*)&zl[row * 768 + ((g ^ (row & 7)) << 3)] =
        *(const short8*)(z + m * 12288 + (size_t)s * 8);
  }
  for (int s = t; s < 1152; s += 256) {
    int row = s / 96, g = s % 96;
    *(short8*)&ql[row * 768 + ((g ^ (row & 7)) << 3)] =
        *(const short8*)(qk + m * 9216 + (size_t)s * 8);
  }
  if (t < 16) il[t] = 1.f / (sqrtf(ssy[m * 16 + t]) + 1e-6f);
  __syncthreads();

  f32x4 c = {0.f, 0.f, 0.f, 0.f};
  #pragma unroll
  for (int i = 0; i < 6; ++i) {
    int gb = wv * 24 + i * 4 + lg;
    short8 a = (lr < 12) ? *(const short8*)&ql[lr * 768 + ((gb ^ (lr & 7)) << 3)]
                         : short8{0, 0, 0, 0, 0, 0, 0, 0};
    short8 b = *(const short8*)&zl[lr * 768 + ((gb ^ (lr & 7)) << 3)];
    c = __builtin_amdgcn_mfma_f32_16x16x32_bf16(a, b, c, 0, 0, 0);
  }
  if (wv > 0) {
    #pragma unroll
    for (int i = 0; i < 4; ++i) sc[wv - 1][(lg * 4 + i) * 16 + lr] = c[i];
  }
  __syncthreads();
  if (wv == 0) {
    #pragma unroll
    for (int i = 0; i < 4; ++i) {
      int idx = (lg * 4 + i) * 16 + lr;
      float s = (c[i] + sc[0][idx] + sc[1][idx] + sc[2][idx]) * il[lr];
      float mx = s;
      #pragma unroll
      for (int off = 1; off < 16; off <<= 1) mx = fmaxf(mx, __shfl_xor(mx, off));
      float e = __expf(s - mx);
      float sum = e;
      #pragma unroll
      for (int off = 1; off < 16; off <<= 1) sum += __shfl_xor(sum, off);
      al[idx] = e / sum * il[lr];
    }
  }
  __syncthreads();

  for (int s = t; s < 1152; s += 256) {
    int h = s / 96, gd = s % 96;
    float acc[8] = {0.f, 0.f, 0.f, 0.f, 0.f, 0.f, 0.f, 0.f};
    #pragma unroll
    for (int w = 0; w < 16; ++w) {
      float aw = al[h * 16 + w];
      short8 zz = *(const short8*)&zl[w * 768 + ((gd ^ (w & 7)) << 3)];
      #pragma unroll
      for (int j = 0; j < 8; ++j) acc[j] += aw * b2f((unsigned short)zz[j]);
    }
    short8 o;
    #pragma unroll
    for (int j = 0; j < 8; ++j) o[j] = (short)f2bs(acc[j]);
    *(short8*)&u[m * 9216 + (size_t)s * 8] = o;
  }
}

__global__ __launch_bounds__(256) void ln_kernel(const float* __restrict__ R,
                                                 const float* __restrict__ w,
                                                 const float* __restrict__ b,
                                                 float* __restrict__ out) {
  const long row = blockIdx.x;
  const int t = threadIdx.x;
  const float* rr = R + row * 768;
  float v0 = rr[t], v1 = rr[t + 256], v2 = rr[t + 512];
  float s = v0 + v1 + v2;
  #pragma unroll
  for (int off = 1; off < 64; off <<= 1) s += __shfl_xor(s, off);
  __shared__ float ps[4];
  __shared__ float ps2[4];
  const int wave = t >> 6, lane = t & 63;
  if (lane == 0) ps[wave] = s;
  __syncthreads();
  const float mean = (ps[0] + ps[1] + ps[2] + ps[3]) * (1.f / 768.f);
  const float d0 = v0 - mean, d1 = v1 - mean, d2 = v2 - mean;
  float q = d0 * d0 + d1 * d1 + d2 * d2;
  #pragma unroll
  for (int off = 1; off < 64; off <<= 1) q += __shfl_xor(q, off);
  if (lane == 0) ps2[wave] = q;
  __syncthreads();
  const float var = (ps2[0] + ps2[1] + ps2[2] + ps2[3]) * (1.f / 768.f);
  const float rs = rsqrtf(var + 1e-6f);
  float* oo = out + row * 768;
  oo[t]       = d0 * rs * w[t]       + b[t];
  oo[t + 256] = d1 * rs * w[t + 256] + b[t + 256];
  oo[t + 512] = d2 * rs * w[t + 512] + b[t + 512];
}

extern "C" void kernel_launch(void* const* d_in, const int* in_sizes, int n_in,
                              void* d_out, int out_size, void* d_ws, size_t ws_size,
                              hipStream_t stream) {
  const float* x   = (const float*)d_in[0];   // (8,1024,1536)
  const float* y   = (const float*)d_in[1];   // (8,16384,1024)
  const float* Wx  = (const float*)d_in[2];   // (768,1536)
  const float* bx  = (const float*)d_in[3];
  const float* Wy  = (const float*)d_in[4];   // (768,1024)
  const float* by  = (const float*)d_in[5];
  const float* ipw = (const float*)d_in[6];   // (2304,768)
  const float* ipb = (const float*)d_in[7];
  const float* Wo  = (const float*)d_in[8];   // (768,768)
  const float* ob  = (const float*)d_in[9];
  const float* lnw = (const float*)d_in[10];
  const float* lnb = (const float*)d_in[11];
  float* out = (float*)d_out;

  char* ws = (char*)d_ws;
  size_t off = 0;
  auto alloc = [&](size_t bytes) {
    void* p = ws + off;
    off += (bytes + 4095) & ~(size_t)4095;
    return p;
  };
  unsigned short* Wx_b  = (unsigned short*)alloc(768L * 1536 * 2);
  unsigned short* Wy_b  = (unsigned short*)alloc(768L * 1024 * 2);
  unsigned short* Wq_b  = (unsigned short*)alloc(768L * 768 * 2);
  unsigned short* WkT_b = (unsigned short*)alloc(768L * 768 * 2);
  unsigned short* Wv_b  = (unsigned short*)alloc(768L * 768 * 2);
  unsigned short* Wo_b  = (unsigned short*)alloc(768L * 768 * 2);
  float* ssx = (float*)alloc(8192L * 4);
  float* ssy = (float*)alloc(131072L * 4);
  unsigned short* z_b  = (unsigned short*)alloc(131072L * 768 * 2);
  unsigned short* xq_b = (unsigned short*)alloc(8192L * 768 * 2);
  char* reg = (char*)alloc(134217728L * 2);    // 256 MB scratch region
  unsigned short* q_b  = (unsigned short*)(reg + 25165824);       // 12.6 MB
  unsigned short* qk_b = (unsigned short*)(reg + 37748736);       // 151 MB (also u)
  unsigned short* o_b  = (unsigned short*)(reg + 188743680);      // 12.6 MB
  float*          r_f  = (float*)(reg + 201326592);               // 25.2 MB
  (void)ws_size; (void)in_sizes; (void)n_in; (void)out_size;

  hipMemsetAsync(ssx, 0, 8192L * 4, stream);
  hipMemsetAsync(ssy, 0, 131072L * 4, stream);

  // all weights -> bf16 in one dispatch (933888 vec4 + 589824 scalar)
  wconv_kernel<<<5952, 256, 0, stream>>>(Wx, Wy, ipw, Wo,
                                         Wx_b, Wy_b, Wq_b, WkT_b, Wv_b, Wo_b);

  // merged dispatch: blocks [0,6144) z = y@Wy^T+by (XCD1D);
  //                  blocks [6144,6528) xq_raw = x@Wx^T+bx. Both + row sumsq.
  gemm_af32_dual<<<6528, 256, 0, stream>>>(
      y, (const short*)Wy_b, z_b, by, ssy, 1024, 6, 6144,
      x, (const short*)Wx_b, xq_b, bx, ssx, 1536);

  // q = rs[m]*(xq_raw @ Wq^T) + bq   (rowscale folded into epilogue), BM=64
  gemm_bt<64, 128, EPI_BF16, false><<<dim3(128, 6, 1), 256, 0, stream>>>(
      (const short*)xq_b, (const short*)Wq_b, q_b, ipb, nullptr, nullptr, ssx,
      768, 768, 768, 768, 1.f, 0, 0, 0, 0, 0);

  // qk[m,h,:] = scale * q[m,h*64:+64] @ WkT[h]   (bk dropped: softmax-invariant)
  gemm_bt<128, 128, EPI_BF16, false><<<dim3(64, 6, 12), 256, 0, stream>>>(
      (const short*)q_b, (const short*)WkT_b, qk_b, nullptr, nullptr, nullptr, nullptr,
      768, 64, 9216, 64, 0.125f, 64, 49152, 768, 0, 0);

  // fused scores/softmax/u  (u overwrites qk slice per token)
  attn_kernel<<<8192, 256, 0, stream>>>(z_b, qk_b, ssy, qk_b);

  // o[:,h*64:+64] = u[:,h,:] @ Wv_h^T + bv_h
  gemm_bt<128, 64, EPI_BF16, false><<<dim3(64, 1, 12), 256, 0, stream>>>(
      (const short*)qk_b, (const short*)Wv_b, o_b, ipb + 1536, nullptr, nullptr, nullptr,
      9216, 768, 768, 768, 1.f, 768, 49152, 64, 64, 0);

  // r = o @ out_w^T + out_b + rs[m]*xq_raw   (residual row-scale), BM=64
  gemm_bt<64, 128, EPI_F32_RESID, false><<<dim3(128, 6, 1), 256, 0, stream>>>(
      (const short*)o_b, (const short*)Wo_b, r_f, ob, xq_b, nullptr, ssx,
      768, 768, 768, 768, 1.f, 0, 0, 0, 0, 0);

  ln_kernel<<<8192, 256, 0, stream>>>(r_f, lnw, lnb, out);
}

// Round 16
// 636.730 us; speedup vs baseline: 1.1866x; 1.0448x over previous
//
#include <hip/hip_runtime.h>
#include <hip/hip_bf16.h>

typedef __attribute__((ext_vector_type(8))) short short8;
typedef __attribute__((ext_vector_type(4))) float f32x4;

static __device__ __forceinline__ float b2f(unsigned short u) {
  return __uint_as_float(((unsigned int)u) << 16);
}
static __device__ __forceinline__ unsigned short f2bs(float f) {
  unsigned int u = __float_as_uint(f);
  u = u + 0x7FFFu + ((u >> 16) & 1u);   // RNE (no NaN inputs here)
  return (unsigned short)(u >> 16);
}
// pair f32 -> packed bf16 (HW v_cvt_pk_bf16_f32, RNE)
static __device__ __forceinline__ unsigned int cvt2(float a, float b) {
  __hip_bfloat162 h = __float22bfloat162_rn(make_float2(a, b));
  return *(unsigned int*)&h;
}

// async global->LDS DMA, 16B per lane; LDS dest = wave-uniform base + lane*16
static __device__ __forceinline__ void gload16(const void* g, void* l) {
  __builtin_amdgcn_global_load_lds(
      (const __attribute__((address_space(1))) void*)g,
      (__attribute__((address_space(3))) void*)l, 16, 0, 0);
}

enum { EPI_BF16_SUMSQ = 1, EPI_BF16 = 2, EPI_F32_RESID = 3 };

// ---------------- bf16-A GEMM (m97 structure, proven Round 6) ----------------
// rowscale (raw sumsq): EPI_BF16 -> v = (acc*escale)*rs + bias;
//                       EPI_F32_RESID -> v = acc + bias + rs*resid.
template<int BM, int BN, int EPI, bool XCD1D>
__global__ __launch_bounds__(256, 4) void gemm_bt(
    const short* __restrict__ A, const short* __restrict__ B, void* __restrict__ Cv,
    const float* __restrict__ bias, const unsigned short* __restrict__ residb,
    float* __restrict__ sumsq, const float* __restrict__ rowscale,
    long lda, long ldb, long ldc, int K, float escale,
    long aZ, long bZ, long cZ, int biasZ, int ncolb)
{
  constexpr int BK = 64;
  constexpr int WM = BM / 2, WN = BN / 2, MR = WM / 16, NR = WN / 16;
  __shared__ __align__(16) short As[BM * BK];
  __shared__ __align__(16) short Bs[BN * BK];
  const int t = threadIdx.x;
  const int zb = blockIdx.z;
  long bxc, byp;
  if constexpr (XCD1D) {
    int bid = blockIdx.x;
    int per = gridDim.x >> 3;
    int ppx = per / ncolb;
    int xcd = bid & 7, j = bid >> 3;
    byp = (long)xcd * ppx + j / ncolb;
    bxc = j % ncolb;
  } else {
    byp = blockIdx.x; bxc = blockIdx.y;
  }
  const long row0 = byp * BM;
  const long col0 = bxc * BN;
  const int wave = t >> 6, lane = t & 63;
  const int wr = wave >> 1, wc = wave & 1;
  const int lr = lane & 15, lg = lane >> 4;
  const short* Az = A + (size_t)zb * aZ;
  const short* Bz = B + (size_t)zb * bZ;
  const int lrow8 = lane >> 3;
  const int lgran = (lane & 7) ^ lrow8;

  auto dmaA = [&](int k0) {
    #pragma unroll
    for (int i = 0; i < BM / 32; ++i) {
      int c = wave * (BM / 32) + i;
      gload16(Az + (size_t)(row0 + c * 8 + lrow8) * lda + k0 + lgran * 8,
              &As[c * 512]);
    }
  };
  auto dmaB = [&](int k0) {
    #pragma unroll
    for (int i = 0; i < BN / 32; ++i) {
      int c = wave * (BN / 32) + i;
      gload16(Bz + (size_t)(col0 + c * 8 + lrow8) * ldb + k0 + lgran * 8,
              &Bs[c * 512]);
    }
  };

  const f32x4 zero4 = {0.f, 0.f, 0.f, 0.f};
  f32x4 acc[MR][NR];
  #pragma unroll
  for (int m = 0; m < MR; ++m)
    #pragma unroll
    for (int n = 0; n < NR; ++n) acc[m][n] = zero4;

  dmaA(0); dmaB(0);
  __syncthreads();

  const int nk = K / BK;
  for (int kt = 0; kt < nk; ++kt) {
    #pragma unroll
    for (int kk = 0; kk < 2; ++kk) {
      short8 a[MR], b[NR];
      #pragma unroll
      for (int m = 0; m < MR; ++m) {
        int row = wr * WM + m * 16 + lr, col = kk * 32 + lg * 8;
        a[m] = *(const short8*)&As[row * 64 + (col ^ ((row & 7) << 3))];
      }
      #pragma unroll
      for (int n = 0; n < NR; ++n) {
        int row = wc * WN + n * 16 + lr, col = kk * 32 + lg * 8;
        b[n] = *(const short8*)&Bs[row * 64 + (col ^ ((row & 7) << 3))];
      }
      #pragma unroll
      for (int m = 0; m < MR; ++m)
        #pragma unroll
        for (int n = 0; n < NR; ++n)
          acc[m][n] = __builtin_amdgcn_mfma_f32_16x16x32_bf16(a[m], b[n], acc[m][n], 0, 0, 0);
    }
    if (kt + 1 < nk) {
      __syncthreads();
      dmaA((kt + 1) * BK); dmaB((kt + 1) * BK);
      __syncthreads();
    }
  }

  const float* biasz = bias ? (bias + (size_t)zb * biasZ) : nullptr;
  float* Cf = (float*)Cv;
  unsigned short* Cb = (unsigned short*)Cv;
  #pragma unroll
  for (int m = 0; m < MR; ++m) {
    #pragma unroll
    for (int i = 0; i < 4; ++i) {
      long row = row0 + wr * WM + m * 16 + lg * 4 + i;
      float rs = 1.f;
      if (rowscale) rs = 1.f / (sqrtf(rowscale[row]) + 1e-6f);
      float sq = 0.f;
      #pragma unroll
      for (int n = 0; n < NR; ++n) {
        long col = col0 + wc * WN + n * 16 + lr;
        float v = acc[m][n][i] * escale;
        size_t ci = (size_t)zb * cZ + (size_t)row * ldc + col;
        if constexpr (EPI == EPI_F32_RESID) {
          v += biasz[col] + rs * b2f(residb[(size_t)row * ldc + col]);
          Cf[ci] = v;
        } else if constexpr (EPI == EPI_BF16_SUMSQ) {
          if (biasz) v += biasz[col];
          Cb[ci] = f2bs(v);
          sq += v * v;
        } else {                      // EPI_BF16
          v *= rs;
          if (biasz) v += biasz[col];
          Cb[ci] = f2bs(v);
        }
      }
      if constexpr (EPI == EPI_BF16_SUMSQ) {
        #pragma unroll
        for (int off = 1; off < 16; off <<= 1) sq += __shfl_xor(sq, off);
        if (lr == 0) atomicAdd(&sumsq[row], sq);
      }
    }
  }
}

// -------- f32-A fused GEMM (Round-8 structure, 4x1 WAVE SPLIT), DUAL dispatch:
// blocks [0,nx): x path (linear, LONGER K -> dispatched FIRST to kill tail);
// blocks [nx,..): z path (XCD1D mapping over nz blocks).
// 4x1 split: wave w owns rows [32w,32w+32) x all 128 cols (MR=2,NR=8) ->
// A-frag LDS reads and cvt_pk HALVED vs 2x2 (no duplicate A work per row-pair).
// A staged raw f32 via global_load_lds, bf16-converted on fragment read.
// Full-rank granule involution: slot g ^ (r&15) -> conflict-free b128 reads.
__global__ __launch_bounds__(256, 3) void gemm_af32_dual(
    const float* __restrict__ A, const short* __restrict__ B,
    unsigned short* __restrict__ C, const float* __restrict__ bias,
    float* __restrict__ sumsq, int K, int ncolb, int nz,
    const float* __restrict__ A2, const short* __restrict__ B2,
    unsigned short* __restrict__ C2, const float* __restrict__ bias2,
    float* __restrict__ sumsq2, int K2)
{
  constexpr int BM = 128, BN = 128, BK = 64, WM = 32, MR = 2, NR = 8;
  __shared__ __align__(16) float Asf[BM * BK];
  __shared__ __align__(16) short Bs[BN * BK];
  const int t = threadIdx.x;
  const int bid = blockIdx.x;
  const int nx = gridDim.x - nz;

  const float* Ap; const short* Bp; unsigned short* Cp;
  const float* biasp; float* ssp; int Kl;
  long bxc, byp;
  if (bid < nx) {              // x path first (K=1536, longest blocks)
    byp = bid / 6; bxc = bid % 6;
    Ap = A2; Bp = B2; Cp = C2; biasp = bias2; ssp = sumsq2; Kl = K2;
  } else {                     // z path: XCD1D over nz blocks
    int zbid = bid - nx;
    int per = nz >> 3;
    int ppx = per / ncolb;
    int xcd = zbid & 7, j = zbid >> 3;
    byp = (long)xcd * ppx + j / ncolb;
    bxc = j % ncolb;
    Ap = A; Bp = B; Cp = C; biasp = bias; ssp = sumsq; Kl = K;
  }
  const long row0 = byp * BM;
  const long col0 = bxc * BN;
  const int wave = t >> 6, lane = t & 63;
  const int lr = lane & 15, lg = lane >> 4;
  const int lrow8 = lane >> 3;
  const int lgran8 = (lane & 7) ^ lrow8;   // B-side (bf16) swizzle
  const int lrow4 = lane >> 4;             // A-side f32: 4 rows per 1KB chunk

  auto dmaAf = [&](int k0) {
    #pragma unroll
    for (int i = 0; i < BM / 16; ++i) {
      int c = wave * (BM / 16) + i;      // 4-row chunk; row = c*4 + lrow4
      // source granule = (lane&15) ^ (row&15); c&3 == i&3 (wave*8 ≡ 0 mod 4)
      int lg16 = (lane & 15) ^ lrow4 ^ ((i & 3) << 2);
      gload16(Ap + (size_t)(row0 + c * 4 + lrow4) * Kl + k0 + lg16 * 4,
              &Asf[c * 256]);
    }
  };
  auto dmaB = [&](int k0) {
    #pragma unroll
    for (int i = 0; i < 4; ++i) {
      int c = wave * 4 + i;              // 8-row chunk
      gload16(Bp + (size_t)(col0 + c * 8 + lrow8) * Kl + k0 + lgran8 * 8,
              &Bs[c * 512]);
    }
  };

  const f32x4 zero4 = {0.f, 0.f, 0.f, 0.f};
  f32x4 acc[MR][NR];
  #pragma unroll
  for (int m = 0; m < MR; ++m)
    #pragma unroll
    for (int n = 0; n < NR; ++n) acc[m][n] = zero4;

  dmaAf(0); dmaB(0);
  __syncthreads();

  const int nk = Kl / BK;
  for (int kt = 0; kt < nk; ++kt) {
    #pragma unroll
    for (int kk = 0; kk < 2; ++kk) {
      short8 a[MR], b[NR];
      #pragma unroll
      for (int m = 0; m < MR; ++m) {
        int row = wave * WM + m * 16 + lr;  // row & 15 == lr
        int j0 = kk * 8 + lg * 2;           // f32 16B-granule index (2 per frag)
        float4 lo = *(const float4*)&Asf[row * 64 + ((j0 ^ lr) << 2)];
        float4 hi = *(const float4*)&Asf[row * 64 + (((j0 + 1) ^ lr) << 2)];
        union { short8 s; unsigned int u[4]; } U;
        U.u[0] = cvt2(lo.x, lo.y); U.u[1] = cvt2(lo.z, lo.w);
        U.u[2] = cvt2(hi.x, hi.y); U.u[3] = cvt2(hi.z, hi.w);
        a[m] = U.s;
      }
      #pragma unroll
      for (int n = 0; n < NR; ++n) {
        int row = n * 16 + lr, col = kk * 32 + lg * 8;
        b[n] = *(const short8*)&Bs[row * 64 + (col ^ ((row & 7) << 3))];
      }
      #pragma unroll
      for (int m = 0; m < MR; ++m)
        #pragma unroll
        for (int n = 0; n < NR; ++n)
          acc[m][n] = __builtin_amdgcn_mfma_f32_16x16x32_bf16(a[m], b[n], acc[m][n], 0, 0, 0);
    }
    if (kt + 1 < nk) {
      __syncthreads();
      dmaAf((kt + 1) * BK); dmaB((kt + 1) * BK);
      __syncthreads();
    }
  }

  #pragma unroll
  for (int m = 0; m < MR; ++m) {
    #pragma unroll
    for (int i = 0; i < 4; ++i) {
      long row = row0 + wave * WM + m * 16 + lg * 4 + i;
      float sq = 0.f;
      #pragma unroll
      for (int n = 0; n < NR; ++n) {
        long col = col0 + n * 16 + lr;
        float v = acc[m][n][i] + biasp[col];
        Cp[(size_t)row * 768 + col] = f2bs(v);
        sq += v * v;
      }
      #pragma unroll
      for (int off = 1; off < 16; off <<= 1) sq += __shfl_xor(sq, off);
      if (lr == 0) atomicAdd(&ssp[row], sq);
    }
  }
}

// all weight conversions in one dispatch; linear parts vectorized (f32x4->short4)
__global__ __launch_bounds__(256) void wconv_kernel(
    const float* __restrict__ Wx, const float* __restrict__ Wy,
    const float* __restrict__ ipw, const float* __restrict__ Wo,
    unsigned short* __restrict__ dWx, unsigned short* __restrict__ dWy,
    unsigned short* __restrict__ dWq, unsigned short* __restrict__ dWkT,
    unsigned short* __restrict__ dWv, unsigned short* __restrict__ dWo)
{
  long i = (long)blockIdx.x * 256 + threadIdx.x;
  if (i < 933888) {            // 4-elem vectorized linear conversions
    const float* s; unsigned short* d; long base = i;
    if (base < 294912) { s = Wx; d = dWx; }
    else if ((base -= 294912) < 196608) { s = Wy; d = dWy; }
    else if ((base -= 196608) < 147456) { s = ipw; d = dWq; }
    else if ((base -= 147456) < 147456) { s = ipw + 2 * 589824; d = dWv; }
    else { base -= 147456; s = Wo; d = dWo; }
    float4 v = ((const float4*)s)[base];
    short4 o;
    o.x = (short)f2bs(v.x); o.y = (short)f2bs(v.y);
    o.z = (short)f2bs(v.z); o.w = (short)f2bs(v.w);
    ((short4*)d)[base] = o;
    return;
  }
  i -= 933888;
  if (i < 589824) {            // WkT[h][n][j] = Wk[h*64+j][n] (gather)
    int h = (int)(i / 49152), r = (int)(i % 49152);
    int nn = r >> 6, j = r & 63;
    dWkT[i] = f2bs(ipw[(size_t)(768 + h * 64 + j) * 768 + nn]);
  }
}

// Per-token fused: S = (qk . z)*invn -> softmax_w -> a = attn*invn -> u = a @ z
// zl/ql staged via global_load_lds with pre-swizzled SOURCE (linear LDS dest):
// flat LDS granule F holds source granule row*96 + ((F%96) ^ (row&7)), row=F/96.
__global__ __launch_bounds__(256) void attn_kernel(
    const unsigned short* __restrict__ z, const unsigned short* __restrict__ qk,
    const float* __restrict__ ssy, unsigned short* __restrict__ u)
{
  __shared__ __align__(16) unsigned short zl[16 * 768];
  __shared__ __align__(16) unsigned short ql[12 * 768];
  __shared__ float sc[3][256];
  __shared__ float al[256];
  __shared__ float il[16];
  const int t = threadIdx.x;
  const long m = blockIdx.x;
  const int wv = t >> 6, lane = t & 63;
  const int lr = lane & 15, lg = lane >> 4;

  const unsigned short* zsrc = z + m * 12288;
  for (int c = wv; c < 24; c += 4) {       // 1536 granules, 64/chunk
    int G = c * 64 + lane;
    int row = G / 96, s = G % 96;
    gload16(zsrc + (size_t)(row * 96 + (s ^ (row & 7))) * 8, &zl[c * 512]);
  }
  const unsigned short* qsrc = qk + m * 9216;
  for (int c = wv; c < 18; c += 4) {       // 1152 granules
    int G = c * 64 + lane;
    int row = G / 96, s = G % 96;
    gload16(qsrc + (size_t)(row * 96 + (s ^ (row & 7))) * 8, &ql[c * 512]);
  }
  if (t < 16) il[t] = 1.f / (sqrtf(ssy[m * 16 + t]) + 1e-6f);
  __syncthreads();

  f32x4 c = {0.f, 0.f, 0.f, 0.f};
  #pragma unroll
  for (int i = 0; i < 6; ++i) {
    int gb = wv * 24 + i * 4 + lg;
    short8 a = (lr < 12) ? *(const short8*)&ql[lr * 768 + ((gb ^ (lr & 7)) << 3)]
                         : short8{0, 0, 0, 0, 0, 0, 0, 0};
    short8 b = *(const short8*)&zl[lr * 768 + ((gb ^ (lr & 7)) << 3)];
    c = __builtin_amdgcn_mfma_f32_16x16x32_bf16(a, b, c, 0, 0, 0);
  }
  if (wv > 0) {
    #pragma unroll
    for (int i = 0; i < 4; ++i) sc[wv - 1][(lg * 4 + i) * 16 + lr] = c[i];
  }
  __syncthreads();
  if (wv == 0) {
    #pragma unroll
    for (int i = 0; i < 4; ++i) {
      int idx = (lg * 4 + i) * 16 + lr;
      float s = (c[i] + sc[0][idx] + sc[1][idx] + sc[2][idx]) * il[lr];
      float mx = s;
      #pragma unroll
      for (int off = 1; off < 16; off <<= 1) mx = fmaxf(mx, __shfl_xor(mx, off));
      float e = __expf(s - mx);
      float sum = e;
      #pragma unroll
      for (int off = 1; off < 16; off <<= 1) sum += __shfl_xor(sum, off);
      al[idx] = e / sum * il[lr];
    }
  }
  __syncthreads();

  for (int s = t; s < 1152; s += 256) {
    int h = s / 96, gd = s % 96;
    float acc[8] = {0.f, 0.f, 0.f, 0.f, 0.f, 0.f, 0.f, 0.f};
    #pragma unroll
    for (int w = 0; w < 16; ++w) {
      float aw = al[h * 16 + w];
      short8 zz = *(const short8*)&zl[w * 768 + ((gd ^ (w & 7)) << 3)];
      #pragma unroll
      for (int j = 0; j < 8; ++j) acc[j] += aw * b2f((unsigned short)zz[j]);
    }
    short8 o;
    #pragma unroll
    for (int j = 0; j < 8; ++j) o[j] = (short)f2bs(acc[j]);
    *(short8*)&u[m * 9216 + (size_t)s * 8] = o;
  }
}

__global__ __launch_bounds__(256) void ln_kernel(const float* __restrict__ R,
                                                 const float* __restrict__ w,
                                                 const float* __restrict__ b,
                                                 float* __restrict__ out) {
  const long row = blockIdx.x;
  const int t = threadIdx.x;
  const float* rr = R + row * 768;
  float v0 = rr[t], v1 = rr[t + 256], v2 = rr[t + 512];
  float s = v0 + v1 + v2;
  #pragma unroll
  for (int off = 1; off < 64; off <<= 1) s += __shfl_xor(s, off);
  __shared__ float ps[4];
  __shared__ float ps2[4];
  const int wave = t >> 6, lane = t & 63;
  if (lane == 0) ps[wave] = s;
  __syncthreads();
  const float mean = (ps[0] + ps[1] + ps[2] + ps[3]) * (1.f / 768.f);
  const float d0 = v0 - mean, d1 = v1 - mean, d2 = v2 - mean;
  float q = d0 * d0 + d1 * d1 + d2 * d2;
  #pragma unroll
  for (int off = 1; off < 64; off <<= 1) q += __shfl_xor(q, off);
  if (lane == 0) ps2[wave] = q;
  __syncthreads();
  const float var = (ps2[0] + ps2[1] + ps2[2] + ps2[3]) * (1.f / 768.f);
  const float rs = rsqrtf(var + 1e-6f);
  float* oo = out + row * 768;
  oo[t]       = d0 * rs * w[t]       + b[t];
  oo[t + 256] = d1 * rs * w[t + 256] + b[t + 256];
  oo[t + 512] = d2 * rs * w[t + 512] + b[t + 512];
}

extern "C" void kernel_launch(void* const* d_in, const int* in_sizes, int n_in,
                              void* d_out, int out_size, void* d_ws, size_t ws_size,
                              hipStream_t stream) {
  const float* x   = (const float*)d_in[0];   // (8,1024,1536)
  const float* y   = (const float*)d_in[1];   // (8,16384,1024)
  const float* Wx  = (const float*)d_in[2];   // (768,1536)
  const float* bx  = (const float*)d_in[3];
  const float* Wy  = (const float*)d_in[4];   // (768,1024)
  const float* by  = (const float*)d_in[5];
  const float* ipw = (const float*)d_in[6];   // (2304,768)
  const float* ipb = (const float*)d_in[7];
  const float* Wo  = (const float*)d_in[8];   // (768,768)
  const float* ob  = (const float*)d_in[9];
  const float* lnw = (const float*)d_in[10];
  const float* lnb = (const float*)d_in[11];
  float* out = (float*)d_out;

  char* ws = (char*)d_ws;
  size_t off = 0;
  auto alloc = [&](size_t bytes) {
    void* p = ws + off;
    off += (bytes + 4095) & ~(size_t)4095;
    return p;
  };
  unsigned short* Wx_b  = (unsigned short*)alloc(768L * 1536 * 2);
  unsigned short* Wy_b  = (unsigned short*)alloc(768L * 1024 * 2);
  unsigned short* Wq_b  = (unsigned short*)alloc(768L * 768 * 2);
  unsigned short* WkT_b = (unsigned short*)alloc(768L * 768 * 2);
  unsigned short* Wv_b  = (unsigned short*)alloc(768L * 768 * 2);
  unsigned short* Wo_b  = (unsigned short*)alloc(768L * 768 * 2);
  float* ssx = (float*)alloc(8192L * 4);
  float* ssy = (float*)alloc(131072L * 4);
  unsigned short* z_b  = (unsigned short*)alloc(131072L * 768 * 2);
  unsigned short* xq_b = (unsigned short*)alloc(8192L * 768 * 2);
  char* reg = (char*)alloc(134217728L * 2);    // 256 MB scratch region
  unsigned short* q_b  = (unsigned short*)(reg + 25165824);       // 12.6 MB
  unsigned short* qk_b = (unsigned short*)(reg + 37748736);       // 151 MB (also u)
  unsigned short* o_b  = (unsigned short*)(reg + 188743680);      // 12.6 MB
  float*          r_f  = (float*)(reg + 201326592);               // 25.2 MB
  (void)ws_size; (void)in_sizes; (void)n_in; (void)out_size;

  hipMemsetAsync(ssx, 0, 8192L * 4, stream);
  hipMemsetAsync(ssy, 0, 131072L * 4, stream);

  // all weights -> bf16 in one dispatch (933888 vec4 + 589824 scalar)
  wconv_kernel<<<5952, 256, 0, stream>>>(Wx, Wy, ipw, Wo,
                                         Wx_b, Wy_b, Wq_b, WkT_b, Wv_b, Wo_b);

  // merged dispatch: blocks [0,384) xq_raw = x@Wx^T+bx (long K, FIRST);
  //                  blocks [384,6528) z = y@Wy^T+by (XCD1D). Both + sumsq.
  gemm_af32_dual<<<6528, 256, 0, stream>>>(
      y, (const short*)Wy_b, z_b, by, ssy, 1024, 6, 6144,
      x, (const short*)Wx_b, xq_b, bx, ssx, 1536);

  // q = rs[m]*(xq_raw @ Wq^T) + bq   (rowscale folded into epilogue), BM=64
  gemm_bt<64, 128, EPI_BF16, false><<<dim3(128, 6, 1), 256, 0, stream>>>(
      (const short*)xq_b, (const short*)Wq_b, q_b, ipb, nullptr, nullptr, ssx,
      768, 768, 768, 768, 1.f, 0, 0, 0, 0, 0);

  // qk[m,h,:] = scale * q[m,h*64:+64] @ WkT[h]   (bk dropped: softmax-invariant)
  gemm_bt<128, 128, EPI_BF16, false><<<dim3(64, 6, 12), 256, 0, stream>>>(
      (const short*)q_b, (const short*)WkT_b, qk_b, nullptr, nullptr, nullptr, nullptr,
      768, 64, 9216, 64, 0.125f, 64, 49152, 768, 0, 0);

  // fused scores/softmax/u  (u overwrites qk slice per token)
  attn_kernel<<<8192, 256, 0, stream>>>(z_b, qk_b, ssy, qk_b);

  // o[:,h*64:+64] = u[:,h,:] @ Wv_h^T + bv_h
  gemm_bt<128, 64, EPI_BF16, false><<<dim3(64, 1, 12), 256, 0, stream>>>(
      (const short*)qk_b, (const short*)Wv_b, o_b, ipb + 1536, nullptr, nullptr, nullptr,
      9216, 768, 768, 768, 1.f, 768, 49152, 64, 64, 0);

  // r = o @ out_w^T + out_b + rs[m]*xq_raw   (residual row-scale), BM=64
  gemm_bt<64, 128, EPI_F32_RESID, false><<<dim3(128, 6, 1), 256, 0, stream>>>(
      (const short*)o_b, (const short*)Wo_b, r_f, ob, xq_b, nullptr, ssx,
      768, 768, 768, 768, 1.f, 0, 0, 0, 0, 0);

  ln_kernel<<<8192, 256, 0, stream>>>(r_f, lnw, lnb, out);
}

// Round 17
// 631.697 us; speedup vs baseline: 1.1960x; 1.0080x over previous
//
#include <hip/hip_runtime.h>
#include <hip/hip_bf16.h>

typedef __attribute__((ext_vector_type(8))) short short8;
typedef __attribute__((ext_vector_type(4))) float f32x4;

static __device__ __forceinline__ float b2f(unsigned short u) {
  return __uint_as_float(((unsigned int)u) << 16);
}
static __device__ __forceinline__ unsigned short f2bs(float f) {
  unsigned int u = __float_as_uint(f);
  u = u + 0x7FFFu + ((u >> 16) & 1u);   // RNE (no NaN inputs here)
  return (unsigned short)(u >> 16);
}
// pair f32 -> packed bf16 (HW v_cvt_pk_bf16_f32, RNE)
static __device__ __forceinline__ unsigned int cvt2(float a, float b) {
  __hip_bfloat162 h = __float22bfloat162_rn(make_float2(a, b));
  return *(unsigned int*)&h;
}

// async global->LDS DMA, 16B per lane; LDS dest = wave-uniform base + lane*16
static __device__ __forceinline__ void gload16(const void* g, void* l) {
  __builtin_amdgcn_global_load_lds(
      (const __attribute__((address_space(1))) void*)g,
      (__attribute__((address_space(3))) void*)l, 16, 0, 0);
}

enum { EPI_BF16_SUMSQ = 1, EPI_BF16 = 2, EPI_BF16_RESID = 3 };

// ---------------- bf16-A GEMM (m97 structure, proven Round 6) ----------------
// rowscale (raw sumsq): EPI_BF16 -> v = (acc*escale)*rs + bias;
//                       EPI_BF16_RESID -> v = acc + bias + rs*resid (bf16 out).
template<int BM, int BN, int EPI, bool XCD1D>
__global__ __launch_bounds__(256, 4) void gemm_bt(
    const short* __restrict__ A, const short* __restrict__ B, void* __restrict__ Cv,
    const float* __restrict__ bias, const unsigned short* __restrict__ residb,
    float* __restrict__ sumsq, const float* __restrict__ rowscale,
    long lda, long ldb, long ldc, int K, float escale,
    long aZ, long bZ, long cZ, int biasZ, int ncolb)
{
  constexpr int BK = 64;
  constexpr int WM = BM / 2, WN = BN / 2, MR = WM / 16, NR = WN / 16;
  __shared__ __align__(16) short As[BM * BK];
  __shared__ __align__(16) short Bs[BN * BK];
  const int t = threadIdx.x;
  const int zb = blockIdx.z;
  long bxc, byp;
  if constexpr (XCD1D) {
    int bid = blockIdx.x;
    int per = gridDim.x >> 3;
    int ppx = per / ncolb;
    int xcd = bid & 7, j = bid >> 3;
    byp = (long)xcd * ppx + j / ncolb;
    bxc = j % ncolb;
  } else {
    byp = blockIdx.x; bxc = blockIdx.y;
  }
  const long row0 = byp * BM;
  const long col0 = bxc * BN;
  const int wave = t >> 6, lane = t & 63;
  const int wr = wave >> 1, wc = wave & 1;
  const int lr = lane & 15, lg = lane >> 4;
  const short* Az = A + (size_t)zb * aZ;
  const short* Bz = B + (size_t)zb * bZ;
  const int lrow8 = lane >> 3;
  const int lgran = (lane & 7) ^ lrow8;

  auto dmaA = [&](int k0) {
    #pragma unroll
    for (int i = 0; i < BM / 32; ++i) {
      int c = wave * (BM / 32) + i;
      gload16(Az + (size_t)(row0 + c * 8 + lrow8) * lda + k0 + lgran * 8,
              &As[c * 512]);
    }
  };
  auto dmaB = [&](int k0) {
    #pragma unroll
    for (int i = 0; i < BN / 32; ++i) {
      int c = wave * (BN / 32) + i;
      gload16(Bz + (size_t)(col0 + c * 8 + lrow8) * ldb + k0 + lgran * 8,
              &Bs[c * 512]);
    }
  };

  const f32x4 zero4 = {0.f, 0.f, 0.f, 0.f};
  f32x4 acc[MR][NR];
  #pragma unroll
  for (int m = 0; m < MR; ++m)
    #pragma unroll
    for (int n = 0; n < NR; ++n) acc[m][n] = zero4;

  dmaA(0); dmaB(0);
  __syncthreads();

  const int nk = K / BK;
  for (int kt = 0; kt < nk; ++kt) {
    #pragma unroll
    for (int kk = 0; kk < 2; ++kk) {
      short8 a[MR], b[NR];
      #pragma unroll
      for (int m = 0; m < MR; ++m) {
        int row = wr * WM + m * 16 + lr, col = kk * 32 + lg * 8;
        a[m] = *(const short8*)&As[row * 64 + (col ^ ((row & 7) << 3))];
      }
      #pragma unroll
      for (int n = 0; n < NR; ++n) {
        int row = wc * WN + n * 16 + lr, col = kk * 32 + lg * 8;
        b[n] = *(const short8*)&Bs[row * 64 + (col ^ ((row & 7) << 3))];
      }
      #pragma unroll
      for (int m = 0; m < MR; ++m)
        #pragma unroll
        for (int n = 0; n < NR; ++n)
          acc[m][n] = __builtin_amdgcn_mfma_f32_16x16x32_bf16(a[m], b[n], acc[m][n], 0, 0, 0);
    }
    if (kt + 1 < nk) {
      __syncthreads();
      dmaA((kt + 1) * BK); dmaB((kt + 1) * BK);
      __syncthreads();
    }
  }

  const float* biasz = bias ? (bias + (size_t)zb * biasZ) : nullptr;
  unsigned short* Cb = (unsigned short*)Cv;
  #pragma unroll
  for (int m = 0; m < MR; ++m) {
    #pragma unroll
    for (int i = 0; i < 4; ++i) {
      long row = row0 + wr * WM + m * 16 + lg * 4 + i;
      float rs = 1.f;
      if (rowscale) rs = 1.f / (sqrtf(rowscale[row]) + 1e-6f);
      float sq = 0.f;
      #pragma unroll
      for (int n = 0; n < NR; ++n) {
        long col = col0 + wc * WN + n * 16 + lr;
        float v = acc[m][n][i] * escale;
        size_t ci = (size_t)zb * cZ + (size_t)row * ldc + col;
        if constexpr (EPI == EPI_BF16_RESID) {
          v += biasz[col] + rs * b2f(residb[(size_t)row * ldc + col]);
          Cb[ci] = f2bs(v);
        } else if constexpr (EPI == EPI_BF16_SUMSQ) {
          if (biasz) v += biasz[col];
          Cb[ci] = f2bs(v);
          sq += v * v;
        } else {                      // EPI_BF16
          v *= rs;
          if (biasz) v += biasz[col];
          Cb[ci] = f2bs(v);
        }
      }
      if constexpr (EPI == EPI_BF16_SUMSQ) {
        #pragma unroll
        for (int off = 1; off < 16; off <<= 1) sq += __shfl_xor(sq, off);
        if (lr == 0) atomicAdd(&sumsq[row], sq);
      }
    }
  }
}

// -------- f32-A fused GEMM (Round-8 structure, 4x1 WAVE SPLIT), DUAL dispatch:
// blocks [0,nx): x path (linear, LONGER K -> dispatched FIRST to kill tail);
// blocks [nx,..): z path (XCD1D mapping over nz blocks).
// 4x1 split: wave w owns rows [32w,32w+32) x all 128 cols (MR=2,NR=8) ->
// A-frag LDS reads and cvt_pk HALVED vs 2x2 (no duplicate A work per row-pair).
// A staged raw f32 via global_load_lds, bf16-converted on fragment read.
// Full-rank granule involution: slot g ^ (r&15) -> conflict-free b128 reads.
__global__ __launch_bounds__(256, 3) void gemm_af32_dual(
    const float* __restrict__ A, const short* __restrict__ B,
    unsigned short* __restrict__ C, const float* __restrict__ bias,
    float* __restrict__ sumsq, int K, int ncolb, int nz,
    const float* __restrict__ A2, const short* __restrict__ B2,
    unsigned short* __restrict__ C2, const float* __restrict__ bias2,
    float* __restrict__ sumsq2, int K2)
{
  constexpr int BM = 128, BN = 128, BK = 64, WM = 32, MR = 2, NR = 8;
  __shared__ __align__(16) float Asf[BM * BK];
  __shared__ __align__(16) short Bs[BN * BK];
  const int t = threadIdx.x;
  const int bid = blockIdx.x;
  const int nx = gridDim.x - nz;

  const float* Ap; const short* Bp; unsigned short* Cp;
  const float* biasp; float* ssp; int Kl;
  long bxc, byp;
  if (bid < nx) {              // x path first (K=1536, longest blocks)
    byp = bid / 6; bxc = bid % 6;
    Ap = A2; Bp = B2; Cp = C2; biasp = bias2; ssp = sumsq2; Kl = K2;
  } else {                     // z path: XCD1D over nz blocks
    int zbid = bid - nx;
    int per = nz >> 3;
    int ppx = per / ncolb;
    int xcd = zbid & 7, j = zbid >> 3;
    byp = (long)xcd * ppx + j / ncolb;
    bxc = j % ncolb;
    Ap = A; Bp = B; Cp = C; biasp = bias; ssp = sumsq; Kl = K;
  }
  const long row0 = byp * BM;
  const long col0 = bxc * BN;
  const int wave = t >> 6, lane = t & 63;
  const int lr = lane & 15, lg = lane >> 4;
  const int lrow8 = lane >> 3;
  const int lgran8 = (lane & 7) ^ lrow8;   // B-side (bf16) swizzle
  const int lrow4 = lane >> 4;             // A-side f32: 4 rows per 1KB chunk

  auto dmaAf = [&](int k0) {
    #pragma unroll
    for (int i = 0; i < BM / 16; ++i) {
      int c = wave * (BM / 16) + i;      // 4-row chunk; row = c*4 + lrow4
      // source granule = (lane&15) ^ (row&15); c&3 == i&3 (wave*8 ≡ 0 mod 4)
      int lg16 = (lane & 15) ^ lrow4 ^ ((i & 3) << 2);
      gload16(Ap + (size_t)(row0 + c * 4 + lrow4) * Kl + k0 + lg16 * 4,
              &Asf[c * 256]);
    }
  };
  auto dmaB = [&](int k0) {
    #pragma unroll
    for (int i = 0; i < 4; ++i) {
      int c = wave * 4 + i;              // 8-row chunk
      gload16(Bp + (size_t)(col0 + c * 8 + lrow8) * Kl + k0 + lgran8 * 8,
              &Bs[c * 512]);
    }
  };

  const f32x4 zero4 = {0.f, 0.f, 0.f, 0.f};
  f32x4 acc[MR][NR];
  #pragma unroll
  for (int m = 0; m < MR; ++m)
    #pragma unroll
    for (int n = 0; n < NR; ++n) acc[m][n] = zero4;

  dmaAf(0); dmaB(0);
  __syncthreads();

  const int nk = Kl / BK;
  for (int kt = 0; kt < nk; ++kt) {
    #pragma unroll
    for (int kk = 0; kk < 2; ++kk) {
      short8 a[MR], b[NR];
      #pragma unroll
      for (int m = 0; m < MR; ++m) {
        int row = wave * WM + m * 16 + lr;  // row & 15 == lr
        int j0 = kk * 8 + lg * 2;           // f32 16B-granule index (2 per frag)
        float4 lo = *(const float4*)&Asf[row * 64 + ((j0 ^ lr) << 2)];
        float4 hi = *(const float4*)&Asf[row * 64 + (((j0 + 1) ^ lr) << 2)];
        union { short8 s; unsigned int u[4]; } U;
        U.u[0] = cvt2(lo.x, lo.y); U.u[1] = cvt2(lo.z, lo.w);
        U.u[2] = cvt2(hi.x, hi.y); U.u[3] = cvt2(hi.z, hi.w);
        a[m] = U.s;
      }
      #pragma unroll
      for (int n = 0; n < NR; ++n) {
        int row = n * 16 + lr, col = kk * 32 + lg * 8;
        b[n] = *(const short8*)&Bs[row * 64 + (col ^ ((row & 7) << 3))];
      }
      #pragma unroll
      for (int m = 0; m < MR; ++m)
        #pragma unroll
        for (int n = 0; n < NR; ++n)
          acc[m][n] = __builtin_amdgcn_mfma_f32_16x16x32_bf16(a[m], b[n], acc[m][n], 0, 0, 0);
    }
    if (kt + 1 < nk) {
      __syncthreads();
      dmaAf((kt + 1) * BK); dmaB((kt + 1) * BK);
      __syncthreads();
    }
  }

  #pragma unroll
  for (int m = 0; m < MR; ++m) {
    #pragma unroll
    for (int i = 0; i < 4; ++i) {
      long row = row0 + wave * WM + m * 16 + lg * 4 + i;
      float sq = 0.f;
      #pragma unroll
      for (int n = 0; n < NR; ++n) {
        long col = col0 + n * 16 + lr;
        float v = acc[m][n][i] + biasp[col];
        Cp[(size_t)row * 768 + col] = f2bs(v);
        sq += v * v;
      }
      #pragma unroll
      for (int off = 1; off < 16; off <<= 1) sq += __shfl_xor(sq, off);
      if (lr == 0) atomicAdd(&ssp[row], sq);
    }
  }
}

// all weight conversions in one dispatch; linear parts vectorized (f32x4->short4)
__global__ __launch_bounds__(256) void wconv_kernel(
    const float* __restrict__ Wx, const float* __restrict__ Wy,
    const float* __restrict__ ipw, const float* __restrict__ Wo,
    unsigned short* __restrict__ dWx, unsigned short* __restrict__ dWy,
    unsigned short* __restrict__ dWq, unsigned short* __restrict__ dWkT,
    unsigned short* __restrict__ dWv, unsigned short* __restrict__ dWo)
{
  long i = (long)blockIdx.x * 256 + threadIdx.x;
  if (i < 933888) {            // 4-elem vectorized linear conversions
    const float* s; unsigned short* d; long base = i;
    if (base < 294912) { s = Wx; d = dWx; }
    else if ((base -= 294912) < 196608) { s = Wy; d = dWy; }
    else if ((base -= 196608) < 147456) { s = ipw; d = dWq; }
    else if ((base -= 147456) < 147456) { s = ipw + 2 * 589824; d = dWv; }
    else { base -= 147456; s = Wo; d = dWo; }
    float4 v = ((const float4*)s)[base];
    short4 o;
    o.x = (short)f2bs(v.x); o.y = (short)f2bs(v.y);
    o.z = (short)f2bs(v.z); o.w = (short)f2bs(v.w);
    ((short4*)d)[base] = o;
    return;
  }
  i -= 933888;
  if (i < 589824) {            // WkT[h][n][j] = Wk[h*64+j][n] (gather)
    int h = (int)(i / 49152), r = (int)(i % 49152);
    int nn = r >> 6, j = r & 63;
    dWkT[i] = f2bs(ipw[(size_t)(768 + h * 64 + j) * 768 + nn]);
  }
}

// Per-token fused: S = (qk . z)*invn -> softmax_w -> a = attn*invn -> u = a @ z
// zl/ql staged via global_load_lds with pre-swizzled SOURCE (linear LDS dest):
// flat LDS granule F holds source granule row*96 + ((F%96) ^ (row&7)), row=F/96.
__global__ __launch_bounds__(256) void attn_kernel(
    const unsigned short* __restrict__ z, const unsigned short* __restrict__ qk,
    const float* __restrict__ ssy, unsigned short* __restrict__ u)
{
  __shared__ __align__(16) unsigned short zl[16 * 768];
  __shared__ __align__(16) unsigned short ql[12 * 768];
  __shared__ float sc[3][256];
  __shared__ float al[256];
  __shared__ float il[16];
  const int t = threadIdx.x;
  const long m = blockIdx.x;
  const int wv = t >> 6, lane = t & 63;
  const int lr = lane & 15, lg = lane >> 4;

  const unsigned short* zsrc = z + m * 12288;
  for (int c = wv; c < 24; c += 4) {       // 1536 granules, 64/chunk
    int G = c * 64 + lane;
    int row = G / 96, s = G % 96;
    gload16(zsrc + (size_t)(row * 96 + (s ^ (row & 7))) * 8, &zl[c * 512]);
  }
  const unsigned short* qsrc = qk + m * 9216;
  for (int c = wv; c < 18; c += 4) {       // 1152 granules
    int G = c * 64 + lane;
    int row = G / 96, s = G % 96;
    gload16(qsrc + (size_t)(row * 96 + (s ^ (row & 7))) * 8, &ql[c * 512]);
  }
  if (t < 16) il[t] = 1.f / (sqrtf(ssy[m * 16 + t]) + 1e-6f);
  __syncthreads();

  f32x4 c = {0.f, 0.f, 0.f, 0.f};
  #pragma unroll
  for (int i = 0; i < 6; ++i) {
    int gb = wv * 24 + i * 4 + lg;
    short8 a = (lr < 12) ? *(const short8*)&ql[lr * 768 + ((gb ^ (lr & 7)) << 3)]
                         : short8{0, 0, 0, 0, 0, 0, 0, 0};
    short8 b = *(const short8*)&zl[lr * 768 + ((gb ^ (lr & 7)) << 3)];
    c = __builtin_amdgcn_mfma_f32_16x16x32_bf16(a, b, c, 0, 0, 0);
  }
  if (wv > 0) {
    #pragma unroll
    for (int i = 0; i < 4; ++i) sc[wv - 1][(lg * 4 + i) * 16 + lr] = c[i];
  }
  __syncthreads();
  if (wv == 0) {
    #pragma unroll
    for (int i = 0; i < 4; ++i) {
      int idx = (lg * 4 + i) * 16 + lr;
      float s = (c[i] + sc[0][idx] + sc[1][idx] + sc[2][idx]) * il[lr];
      float mx = s;
      #pragma unroll
      for (int off = 1; off < 16; off <<= 1) mx = fmaxf(mx, __shfl_xor(mx, off));
      float e = __expf(s - mx);
      float sum = e;
      #pragma unroll
      for (int off = 1; off < 16; off <<= 1) sum += __shfl_xor(sum, off);
      al[idx] = e / sum * il[lr];
    }
  }
  __syncthreads();

  for (int s = t; s < 1152; s += 256) {
    int h = s / 96, gd = s % 96;
    float acc[8] = {0.f, 0.f, 0.f, 0.f, 0.f, 0.f, 0.f, 0.f};
    #pragma unroll
    for (int w = 0; w < 16; ++w) {
      float aw = al[h * 16 + w];
      short8 zz = *(const short8*)&zl[w * 768 + ((gd ^ (w & 7)) << 3)];
      #pragma unroll
      for (int j = 0; j < 8; ++j) acc[j] += aw * b2f((unsigned short)zz[j]);
    }
    short8 o;
    #pragma unroll
    for (int j = 0; j < 8; ++j) o[j] = (short)f2bs(acc[j]);
    *(short8*)&u[m * 9216 + (size_t)s * 8] = o;
  }
}

// LayerNorm: 4 rows/block, one WAVE per row (no barriers), bf16 input,
// vectorized loads (short4 / float4).
__global__ __launch_bounds__(256) void ln_kernel(const unsigned short* __restrict__ R,
                                                 const float* __restrict__ w,
                                                 const float* __restrict__ b,
                                                 float* __restrict__ out) {
  const int t = threadIdx.x;
  const int wave = t >> 6, lane = t & 63;
  const long row = (long)blockIdx.x * 4 + wave;
  const short4* rr = (const short4*)(R + row * 768);   // 192 short4 per row
  float v[12];
  #pragma unroll
  for (int j = 0; j < 3; ++j) {
    short4 p = rr[lane + 64 * j];
    v[j * 4 + 0] = b2f((unsigned short)p.x);
    v[j * 4 + 1] = b2f((unsigned short)p.y);
    v[j * 4 + 2] = b2f((unsigned short)p.z);
    v[j * 4 + 3] = b2f((unsigned short)p.w);
  }
  float s = 0.f;
  #pragma unroll
  for (int k = 0; k < 12; ++k) s += v[k];
  #pragma unroll
  for (int off = 1; off < 64; off <<= 1) s += __shfl_xor(s, off);
  const float mean = s * (1.f / 768.f);
  float q = 0.f;
  #pragma unroll
  for (int k = 0; k < 12; ++k) { v[k] -= mean; q += v[k] * v[k]; }
  #pragma unroll
  for (int off = 1; off < 64; off <<= 1) q += __shfl_xor(q, off);
  const float rs = rsqrtf(q * (1.f / 768.f) + 1e-6f);
  const float4* w4 = (const float4*)w;
  const float4* b4 = (const float4*)b;
  float4* o4 = (float4*)(out + row * 768);
  #pragma unroll
  for (int j = 0; j < 3; ++j) {
    int g = lane + 64 * j;
    float4 ww = w4[g], bb = b4[g], oo;
    oo.x = v[j * 4 + 0] * rs * ww.x + bb.x;
    oo.y = v[j * 4 + 1] * rs * ww.y + bb.y;
    oo.z = v[j * 4 + 2] * rs * ww.z + bb.z;
    oo.w = v[j * 4 + 3] * rs * ww.w + bb.w;
    o4[g] = oo;
  }
}

extern "C" void kernel_launch(void* const* d_in, const int* in_sizes, int n_in,
                              void* d_out, int out_size, void* d_ws, size_t ws_size,
                              hipStream_t stream) {
  const float* x   = (const float*)d_in[0];   // (8,1024,1536)
  const float* y   = (const float*)d_in[1];   // (8,16384,1024)
  const float* Wx  = (const float*)d_in[2];   // (768,1536)
  const float* bx  = (const float*)d_in[3];
  const float* Wy  = (const float*)d_in[4];   // (768,1024)
  const float* by  = (const float*)d_in[5];
  const float* ipw = (const float*)d_in[6];   // (2304,768)
  const float* ipb = (const float*)d_in[7];
  const float* Wo  = (const float*)d_in[8];   // (768,768)
  const float* ob  = (const float*)d_in[9];
  const float* lnw = (const float*)d_in[10];
  const float* lnb = (const float*)d_in[11];
  float* out = (float*)d_out;

  char* ws = (char*)d_ws;
  size_t off = 0;
  auto alloc = [&](size_t bytes) {
    void* p = ws + off;
    off += (bytes + 4095) & ~(size_t)4095;
    return p;
  };
  unsigned short* Wx_b  = (unsigned short*)alloc(768L * 1536 * 2);
  unsigned short* Wy_b  = (unsigned short*)alloc(768L * 1024 * 2);
  unsigned short* Wq_b  = (unsigned short*)alloc(768L * 768 * 2);
  unsigned short* WkT_b = (unsigned short*)alloc(768L * 768 * 2);
  unsigned short* Wv_b  = (unsigned short*)alloc(768L * 768 * 2);
  unsigned short* Wo_b  = (unsigned short*)alloc(768L * 768 * 2);
  float* ssx = (float*)alloc(8192L * 4);
  float* ssy = (float*)alloc(131072L * 4);
  unsigned short* z_b  = (unsigned short*)alloc(131072L * 768 * 2);
  unsigned short* xq_b = (unsigned short*)alloc(8192L * 768 * 2);
  char* reg = (char*)alloc(134217728L * 2);    // 256 MB scratch region
  unsigned short* q_b  = (unsigned short*)(reg + 25165824);       // 12.6 MB
  unsigned short* qk_b = (unsigned short*)(reg + 37748736);       // 151 MB (also u)
  unsigned short* o_b  = (unsigned short*)(reg + 188743680);      // 12.6 MB
  unsigned short* r_b  = (unsigned short*)(reg + 201326592);      // 12.6 MB (bf16)
  (void)ws_size; (void)in_sizes; (void)n_in; (void)out_size;

  hipMemsetAsync(ssx, 0, 8192L * 4, stream);
  hipMemsetAsync(ssy, 0, 131072L * 4, stream);

  // all weights -> bf16 in one dispatch (933888 vec4 + 589824 scalar)
  wconv_kernel<<<5952, 256, 0, stream>>>(Wx, Wy, ipw, Wo,
                                         Wx_b, Wy_b, Wq_b, WkT_b, Wv_b, Wo_b);

  // merged dispatch: blocks [0,384) xq_raw = x@Wx^T+bx (long K, FIRST);
  //                  blocks [384,6528) z = y@Wy^T+by (XCD1D). Both + sumsq.
  gemm_af32_dual<<<6528, 256, 0, stream>>>(
      y, (const short*)Wy_b, z_b, by, ssy, 1024, 6, 6144,
      x, (const short*)Wx_b, xq_b, bx, ssx, 1536);

  // q = rs[m]*(xq_raw @ Wq^T) + bq   (rowscale folded into epilogue), BM=64
  gemm_bt<64, 128, EPI_BF16, false><<<dim3(128, 6, 1), 256, 0, stream>>>(
      (const short*)xq_b, (const short*)Wq_b, q_b, ipb, nullptr, nullptr, ssx,
      768, 768, 768, 768, 1.f, 0, 0, 0, 0, 0);

  // qk[m,h,:] = scale * q[m,h*64:+64] @ WkT[h]   (bk dropped: softmax-invariant)
  gemm_bt<128, 128, EPI_BF16, false><<<dim3(64, 6, 12), 256, 0, stream>>>(
      (const short*)q_b, (const short*)WkT_b, qk_b, nullptr, nullptr, nullptr, nullptr,
      768, 64, 9216, 64, 0.125f, 64, 49152, 768, 0, 0);

  // fused scores/softmax/u  (u overwrites qk slice per token)
  attn_kernel<<<8192, 256, 0, stream>>>(z_b, qk_b, ssy, qk_b);

  // o[:,h*64:+64] = u[:,h,:] @ Wv_h^T + bv_h
  gemm_bt<128, 64, EPI_BF16, false><<<dim3(64, 1, 12), 256, 0, stream>>>(
      (const short*)qk_b, (const short*)Wv_b, o_b, ipb + 1536, nullptr, nullptr, nullptr,
      9216, 768, 768, 768, 1.f, 768, 49152, 64, 64, 0);

  // r = o @ out_w^T + out_b + rs[m]*xq_raw   (bf16 residual out), BM=64
  gemm_bt<64, 128, EPI_BF16_RESID, false><<<dim3(128, 6, 1), 256, 0, stream>>>(
      (const short*)o_b, (const short*)Wo_b, r_b, ob, xq_b, nullptr, ssx,
      768, 768, 768, 768, 1.f, 0, 0, 0, 0, 0);

  // LayerNorm: 4 rows/block, wave-per-row, bf16 in / f32 out
  ln_kernel<<<2048, 256, 0, stream>>>(r_b, lnw, lnb, out);
}

// Round 18
// 627.743 us; speedup vs baseline: 1.2036x; 1.0063x over previous
//
#include <hip/hip_runtime.h>
#include <hip/hip_bf16.h>

typedef __attribute__((ext_vector_type(8))) short short8;
typedef __attribute__((ext_vector_type(4))) float f32x4;

static __device__ __forceinline__ float b2f(unsigned short u) {
  return __uint_as_float(((unsigned int)u) << 16);
}
static __device__ __forceinline__ unsigned short f2bs(float f) {
  unsigned int u = __float_as_uint(f);
  u = u + 0x7FFFu + ((u >> 16) & 1u);   // RNE (no NaN inputs here)
  return (unsigned short)(u >> 16);
}
// pair f32 -> packed bf16 (HW v_cvt_pk_bf16_f32, RNE)
static __device__ __forceinline__ unsigned int cvt2(float a, float b) {
  __hip_bfloat162 h = __float22bfloat162_rn(make_float2(a, b));
  return *(unsigned int*)&h;
}

// async global->LDS DMA, 16B per lane; LDS dest = wave-uniform base + lane*16
static __device__ __forceinline__ void gload16(const void* g, void* l) {
  __builtin_amdgcn_global_load_lds(
      (const __attribute__((address_space(1))) void*)g,
      (__attribute__((address_space(3))) void*)l, 16, 0, 0);
}

enum { EPI_BF16_SUMSQ = 1, EPI_BF16 = 2, EPI_BF16_RESID = 3 };

// ---------------- bf16-A GEMM (m97 structure, proven Round 6) ----------------
// rowscale (raw sumsq): EPI_BF16 -> v = (acc*escale)*rs + bias;
//                       EPI_BF16_RESID -> v = acc + bias + rs*resid (bf16 out).
template<int BM, int BN, int EPI, bool XCD1D>
__global__ __launch_bounds__(256, 4) void gemm_bt(
    const short* __restrict__ A, const short* __restrict__ B, void* __restrict__ Cv,
    const float* __restrict__ bias, const unsigned short* __restrict__ residb,
    float* __restrict__ sumsq, const float* __restrict__ rowscale,
    long lda, long ldb, long ldc, int K, float escale,
    long aZ, long bZ, long cZ, int biasZ, int ncolb)
{
  constexpr int BK = 64;
  constexpr int WM = BM / 2, WN = BN / 2, MR = WM / 16, NR = WN / 16;
  __shared__ __align__(16) short As[BM * BK];
  __shared__ __align__(16) short Bs[BN * BK];
  const int t = threadIdx.x;
  const int zb = blockIdx.z;
  long bxc, byp;
  if constexpr (XCD1D) {
    int bid = blockIdx.x;
    int per = gridDim.x >> 3;
    int ppx = per / ncolb;
    int xcd = bid & 7, j = bid >> 3;
    byp = (long)xcd * ppx + j / ncolb;
    bxc = j % ncolb;
  } else {
    byp = blockIdx.x; bxc = blockIdx.y;
  }
  const long row0 = byp * BM;
  const long col0 = bxc * BN;
  const int wave = t >> 6, lane = t & 63;
  const int wr = wave >> 1, wc = wave & 1;
  const int lr = lane & 15, lg = lane >> 4;
  const short* Az = A + (size_t)zb * aZ;
  const short* Bz = B + (size_t)zb * bZ;
  const int lrow8 = lane >> 3;
  const int lgran = (lane & 7) ^ lrow8;

  auto dmaA = [&](int k0) {
    #pragma unroll
    for (int i = 0; i < BM / 32; ++i) {
      int c = wave * (BM / 32) + i;
      gload16(Az + (size_t)(row0 + c * 8 + lrow8) * lda + k0 + lgran * 8,
              &As[c * 512]);
    }
  };
  auto dmaB = [&](int k0) {
    #pragma unroll
    for (int i = 0; i < BN / 32; ++i) {
      int c = wave * (BN / 32) + i;
      gload16(Bz + (size_t)(col0 + c * 8 + lrow8) * ldb + k0 + lgran * 8,
              &Bs[c * 512]);
    }
  };

  const f32x4 zero4 = {0.f, 0.f, 0.f, 0.f};
  f32x4 acc[MR][NR];
  #pragma unroll
  for (int m = 0; m < MR; ++m)
    #pragma unroll
    for (int n = 0; n < NR; ++n) acc[m][n] = zero4;

  dmaA(0); dmaB(0);
  __syncthreads();

  const int nk = K / BK;
  for (int kt = 0; kt < nk; ++kt) {
    #pragma unroll
    for (int kk = 0; kk < 2; ++kk) {
      short8 a[MR], b[NR];
      #pragma unroll
      for (int m = 0; m < MR; ++m) {
        int row = wr * WM + m * 16 + lr, col = kk * 32 + lg * 8;
        a[m] = *(const short8*)&As[row * 64 + (col ^ ((row & 7) << 3))];
      }
      #pragma unroll
      for (int n = 0; n < NR; ++n) {
        int row = wc * WN + n * 16 + lr, col = kk * 32 + lg * 8;
        b[n] = *(const short8*)&Bs[row * 64 + (col ^ ((row & 7) << 3))];
      }
      #pragma unroll
      for (int m = 0; m < MR; ++m)
        #pragma unroll
        for (int n = 0; n < NR; ++n)
          acc[m][n] = __builtin_amdgcn_mfma_f32_16x16x32_bf16(a[m], b[n], acc[m][n], 0, 0, 0);
    }
    if (kt + 1 < nk) {
      __syncthreads();
      dmaA((kt + 1) * BK); dmaB((kt + 1) * BK);
      __syncthreads();
    }
  }

  const float* biasz = bias ? (bias + (size_t)zb * biasZ) : nullptr;
  unsigned short* Cb = (unsigned short*)Cv;
  #pragma unroll
  for (int m = 0; m < MR; ++m) {
    #pragma unroll
    for (int i = 0; i < 4; ++i) {
      long row = row0 + wr * WM + m * 16 + lg * 4 + i;
      float rs = 1.f;
      if (rowscale) rs = 1.f / (sqrtf(rowscale[row]) + 1e-6f);
      float sq = 0.f;
      #pragma unroll
      for (int n = 0; n < NR; ++n) {
        long col = col0 + wc * WN + n * 16 + lr;
        float v = acc[m][n][i] * escale;
        size_t ci = (size_t)zb * cZ + (size_t)row * ldc + col;
        if constexpr (EPI == EPI_BF16_RESID) {
          v += biasz[col] + rs * b2f(residb[(size_t)row * ldc + col]);
          Cb[ci] = f2bs(v);
        } else if constexpr (EPI == EPI_BF16_SUMSQ) {
          if (biasz) v += biasz[col];
          Cb[ci] = f2bs(v);
          sq += v * v;
        } else {                      // EPI_BF16
          v *= rs;
          if (biasz) v += biasz[col];
          Cb[ci] = f2bs(v);
        }
      }
      if constexpr (EPI == EPI_BF16_SUMSQ) {
        #pragma unroll
        for (int off = 1; off < 16; off <<= 1) sq += __shfl_xor(sq, off);
        if (lr == 0) atomicAdd(&sumsq[row], sq);
      }
    }
  }
}

// -------- f32-A fused GEMM (Round-8 structure, 4x1 WAVE SPLIT), DUAL dispatch:
// blocks [0,nx): x path (linear, LONGER K -> dispatched FIRST to kill tail);
// blocks [nx,..): z path (XCD1D mapping over nz blocks).
// 4x1 split: wave w owns rows [32w,32w+32) x all 128 cols (MR=2,NR=8) ->
// A-frag LDS reads and cvt_pk HALVED vs 2x2 (no duplicate A work per row-pair).
// A staged raw f32 via global_load_lds, bf16-converted on fragment read.
// Full-rank granule involution: slot g ^ (r&15) -> conflict-free b128 reads.
__global__ __launch_bounds__(256, 3) void gemm_af32_dual(
    const float* __restrict__ A, const short* __restrict__ B,
    unsigned short* __restrict__ C, const float* __restrict__ bias,
    float* __restrict__ sumsq, int K, int ncolb, int nz,
    const float* __restrict__ A2, const short* __restrict__ B2,
    unsigned short* __restrict__ C2, const float* __restrict__ bias2,
    float* __restrict__ sumsq2, int K2)
{
  constexpr int BM = 128, BN = 128, BK = 64, WM = 32, MR = 2, NR = 8;
  __shared__ __align__(16) float Asf[BM * BK];
  __shared__ __align__(16) short Bs[BN * BK];
  const int t = threadIdx.x;
  const int bid = blockIdx.x;
  const int nx = gridDim.x - nz;

  const float* Ap; const short* Bp; unsigned short* Cp;
  const float* biasp; float* ssp; int Kl;
  long bxc, byp;
  if (bid < nx) {              // x path first (K=1536, longest blocks)
    byp = bid / 6; bxc = bid % 6;
    Ap = A2; Bp = B2; Cp = C2; biasp = bias2; ssp = sumsq2; Kl = K2;
  } else {                     // z path: XCD1D over nz blocks
    int zbid = bid - nx;
    int per = nz >> 3;
    int ppx = per / ncolb;
    int xcd = zbid & 7, j = zbid >> 3;
    byp = (long)xcd * ppx + j / ncolb;
    bxc = j % ncolb;
    Ap = A; Bp = B; Cp = C; biasp = bias; ssp = sumsq; Kl = K;
  }
  const long row0 = byp * BM;
  const long col0 = bxc * BN;
  const int wave = t >> 6, lane = t & 63;
  const int lr = lane & 15, lg = lane >> 4;
  const int lrow8 = lane >> 3;
  const int lgran8 = (lane & 7) ^ lrow8;   // B-side (bf16) swizzle
  const int lrow4 = lane >> 4;             // A-side f32: 4 rows per 1KB chunk

  auto dmaAf = [&](int k0) {
    #pragma unroll
    for (int i = 0; i < BM / 16; ++i) {
      int c = wave * (BM / 16) + i;      // 4-row chunk; row = c*4 + lrow4
      // source granule = (lane&15) ^ (row&15); c&3 == i&3 (wave*8 ≡ 0 mod 4)
      int lg16 = (lane & 15) ^ lrow4 ^ ((i & 3) << 2);
      gload16(Ap + (size_t)(row0 + c * 4 + lrow4) * Kl + k0 + lg16 * 4,
              &Asf[c * 256]);
    }
  };
  auto dmaB = [&](int k0) {
    #pragma unroll
    for (int i = 0; i < 4; ++i) {
      int c = wave * 4 + i;              // 8-row chunk
      gload16(Bp + (size_t)(col0 + c * 8 + lrow8) * Kl + k0 + lgran8 * 8,
              &Bs[c * 512]);
    }
  };

  const f32x4 zero4 = {0.f, 0.f, 0.f, 0.f};
  f32x4 acc[MR][NR];
  #pragma unroll
  for (int m = 0; m < MR; ++m)
    #pragma unroll
    for (int n = 0; n < NR; ++n) acc[m][n] = zero4;

  dmaAf(0); dmaB(0);
  __syncthreads();

  const int nk = Kl / BK;
  for (int kt = 0; kt < nk; ++kt) {
    #pragma unroll
    for (int kk = 0; kk < 2; ++kk) {
      short8 a[MR], b[NR];
      #pragma unroll
      for (int m = 0; m < MR; ++m) {
        int row = wave * WM + m * 16 + lr;  // row & 15 == lr
        int j0 = kk * 8 + lg * 2;           // f32 16B-granule index (2 per frag)
        float4 lo = *(const float4*)&Asf[row * 64 + ((j0 ^ lr) << 2)];
        float4 hi = *(const float4*)&Asf[row * 64 + (((j0 + 1) ^ lr) << 2)];
        union { short8 s; unsigned int u[4]; } U;
        U.u[0] = cvt2(lo.x, lo.y); U.u[1] = cvt2(lo.z, lo.w);
        U.u[2] = cvt2(hi.x, hi.y); U.u[3] = cvt2(hi.z, hi.w);
        a[m] = U.s;
      }
      #pragma unroll
      for (int n = 0; n < NR; ++n) {
        int row = n * 16 + lr, col = kk * 32 + lg * 8;
        b[n] = *(const short8*)&Bs[row * 64 + (col ^ ((row & 7) << 3))];
      }
      #pragma unroll
      for (int m = 0; m < MR; ++m)
        #pragma unroll
        for (int n = 0; n < NR; ++n)
          acc[m][n] = __builtin_amdgcn_mfma_f32_16x16x32_bf16(a[m], b[n], acc[m][n], 0, 0, 0);
    }
    if (kt + 1 < nk) {
      __syncthreads();
      dmaAf((kt + 1) * BK); dmaB((kt + 1) * BK);
      __syncthreads();
    }
  }

  #pragma unroll
  for (int m = 0; m < MR; ++m) {
    #pragma unroll
    for (int i = 0; i < 4; ++i) {
      long row = row0 + wave * WM + m * 16 + lg * 4 + i;
      float sq = 0.f;
      #pragma unroll
      for (int n = 0; n < NR; ++n) {
        long col = col0 + n * 16 + lr;
        float v = acc[m][n][i] + biasp[col];
        Cp[(size_t)row * 768 + col] = f2bs(v);
        sq += v * v;
      }
      #pragma unroll
      for (int off = 1; off < 16; off <<= 1) sq += __shfl_xor(sq, off);
      if (lr == 0) atomicAdd(&ssp[row], sq);
    }
  }
}

// all weight conversions + sumsq-buffer zeroing in one dispatch
__global__ __launch_bounds__(256) void wconv_kernel(
    const float* __restrict__ Wx, const float* __restrict__ Wy,
    const float* __restrict__ ipw, const float* __restrict__ Wo,
    unsigned short* __restrict__ dWx, unsigned short* __restrict__ dWy,
    unsigned short* __restrict__ dWq, unsigned short* __restrict__ dWkT,
    unsigned short* __restrict__ dWv, unsigned short* __restrict__ dWo,
    float* __restrict__ ssx, float* __restrict__ ssy)
{
  long i = (long)blockIdx.x * 256 + threadIdx.x;
  if (i < 933888) {            // 4-elem vectorized linear conversions
    const float* s; unsigned short* d; long base = i;
    if (base < 294912) { s = Wx; d = dWx; }
    else if ((base -= 294912) < 196608) { s = Wy; d = dWy; }
    else if ((base -= 196608) < 147456) { s = ipw; d = dWq; }
    else if ((base -= 147456) < 147456) { s = ipw + 2 * 589824; d = dWv; }
    else { base -= 147456; s = Wo; d = dWo; }
    float4 v = ((const float4*)s)[base];
    short4 o;
    o.x = (short)f2bs(v.x); o.y = (short)f2bs(v.y);
    o.z = (short)f2bs(v.z); o.w = (short)f2bs(v.w);
    ((short4*)d)[base] = o;
    return;
  }
  i -= 933888;
  if (i < 589824) {            // WkT[h][n][j] = Wk[h*64+j][n] (gather)
    int h = (int)(i / 49152), r = (int)(i % 49152);
    int nn = r >> 6, j = r & 63;
    dWkT[i] = f2bs(ipw[(size_t)(768 + h * 64 + j) * 768 + nn]);
    return;
  }
  i -= 589824;
  const float4 z4 = {0.f, 0.f, 0.f, 0.f};
  if (i < 32768) { ((float4*)ssy)[i] = z4; return; }   // 131072 f32
  i -= 32768;
  if (i < 2048)  { ((float4*)ssx)[i] = z4; }           // 8192 f32
}

// Per-token fused: S = (qk . z)*invn -> softmax_w -> a = attn*invn -> u = a @ z
// zl/ql staged via global_load_lds with pre-swizzled SOURCE (linear LDS dest):
// flat LDS granule F holds source granule row*96 + ((F%96) ^ (row&7)), row=F/96.
__global__ __launch_bounds__(256) void attn_kernel(
    const unsigned short* __restrict__ z, const unsigned short* __restrict__ qk,
    const float* __restrict__ ssy, unsigned short* __restrict__ u)
{
  __shared__ __align__(16) unsigned short zl[16 * 768];
  __shared__ __align__(16) unsigned short ql[12 * 768];
  __shared__ float sc[3][256];
  __shared__ float al[256];
  __shared__ float il[16];
  const int t = threadIdx.x;
  const long m = blockIdx.x;
  const int wv = t >> 6, lane = t & 63;
  const int lr = lane & 15, lg = lane >> 4;

  float myil = 0.f;                          // issue ssy load before DMA loops
  if (t < 16) myil = ssy[m * 16 + t];

  const unsigned short* zsrc = z + m * 12288;
  for (int c = wv; c < 24; c += 4) {       // 1536 granules, 64/chunk
    int G = c * 64 + lane;
    int row = G / 96, s = G % 96;
    gload16(zsrc + (size_t)(row * 96 + (s ^ (row & 7))) * 8, &zl[c * 512]);
  }
  const unsigned short* qsrc = qk + m * 9216;
  for (int c = wv; c < 18; c += 4) {       // 1152 granules
    int G = c * 64 + lane;
    int row = G / 96, s = G % 96;
    gload16(qsrc + (size_t)(row * 96 + (s ^ (row & 7))) * 8, &ql[c * 512]);
  }
  if (t < 16) il[t] = 1.f / (sqrtf(myil) + 1e-6f);
  __syncthreads();

  f32x4 c = {0.f, 0.f, 0.f, 0.f};
  #pragma unroll
  for (int i = 0; i < 6; ++i) {
    int gb = wv * 24 + i * 4 + lg;
    short8 a = (lr < 12) ? *(const short8*)&ql[lr * 768 + ((gb ^ (lr & 7)) << 3)]
                         : short8{0, 0, 0, 0, 0, 0, 0, 0};
    short8 b = *(const short8*)&zl[lr * 768 + ((gb ^ (lr & 7)) << 3)];
    c = __builtin_amdgcn_mfma_f32_16x16x32_bf16(a, b, c, 0, 0, 0);
  }
  if (wv > 0) {
    #pragma unroll
    for (int i = 0; i < 4; ++i) sc[wv - 1][(lg * 4 + i) * 16 + lr] = c[i];
  }
  __syncthreads();
  if (wv == 0) {
    #pragma unroll
    for (int i = 0; i < 4; ++i) {
      int idx = (lg * 4 + i) * 16 + lr;
      float s = (c[i] + sc[0][idx] + sc[1][idx] + sc[2][idx]) * il[lr];
      float mx = s;
      #pragma unroll
      for (int off = 1; off < 16; off <<= 1) mx = fmaxf(mx, __shfl_xor(mx, off));
      float e = __expf(s - mx);
      float sum = e;
      #pragma unroll
      for (int off = 1; off < 16; off <<= 1) sum += __shfl_xor(sum, off);
      al[idx] = e / sum * il[lr];
    }
  }
  __syncthreads();

  for (int s = t; s < 1152; s += 256) {
    int h = s / 96, gd = s % 96;
    float acc[8] = {0.f, 0.f, 0.f, 0.f, 0.f, 0.f, 0.f, 0.f};
    #pragma unroll
    for (int w = 0; w < 16; ++w) {
      float aw = al[h * 16 + w];
      short8 zz = *(const short8*)&zl[w * 768 + ((gd ^ (w & 7)) << 3)];
      #pragma unroll
      for (int j = 0; j < 8; ++j) acc[j] += aw * b2f((unsigned short)zz[j]);
    }
    short8 o;
    #pragma unroll
    for (int j = 0; j < 8; ++j) o[j] = (short)f2bs(acc[j]);
    *(short8*)&u[m * 9216 + (size_t)s * 8] = o;
  }
}

// LayerNorm: 4 rows/block, one WAVE per row (no barriers), bf16 input,
// vectorized loads (short4 / float4).
__global__ __launch_bounds__(256) void ln_kernel(const unsigned short* __restrict__ R,
                                                 const float* __restrict__ w,
                                                 const float* __restrict__ b,
                                                 float* __restrict__ out) {
  const int t = threadIdx.x;
  const int wave = t >> 6, lane = t & 63;
  const long row = (long)blockIdx.x * 4 + wave;
  const short4* rr = (const short4*)(R + row * 768);   // 192 short4 per row
  float v[12];
  #pragma unroll
  for (int j = 0; j < 3; ++j) {
    short4 p = rr[lane + 64 * j];
    v[j * 4 + 0] = b2f((unsigned short)p.x);
    v[j * 4 + 1] = b2f((unsigned short)p.y);
    v[j * 4 + 2] = b2f((unsigned short)p.z);
    v[j * 4 + 3] = b2f((unsigned short)p.w);
  }
  float s = 0.f;
  #pragma unroll
  for (int k = 0; k < 12; ++k) s += v[k];
  #pragma unroll
  for (int off = 1; off < 64; off <<= 1) s += __shfl_xor(s, off);
  const float mean = s * (1.f / 768.f);
  float q = 0.f;
  #pragma unroll
  for (int k = 0; k < 12; ++k) { v[k] -= mean; q += v[k] * v[k]; }
  #pragma unroll
  for (int off = 1; off < 64; off <<= 1) q += __shfl_xor(q, off);
  const float rs = rsqrtf(q * (1.f / 768.f) + 1e-6f);
  const float4* w4 = (const float4*)w;
  const float4* b4 = (const float4*)b;
  float4* o4 = (float4*)(out + row * 768);
  #pragma unroll
  for (int j = 0; j < 3; ++j) {
    int g = lane + 64 * j;
    float4 ww = w4[g], bb = b4[g], oo;
    oo.x = v[j * 4 + 0] * rs * ww.x + bb.x;
    oo.y = v[j * 4 + 1] * rs * ww.y + bb.y;
    oo.z = v[j * 4 + 2] * rs * ww.z + bb.z;
    oo.w = v[j * 4 + 3] * rs * ww.w + bb.w;
    o4[g] = oo;
  }
}

extern "C" void kernel_launch(void* const* d_in, const int* in_sizes, int n_in,
                              void* d_out, int out_size, void* d_ws, size_t ws_size,
                              hipStream_t stream) {
  const float* x   = (const float*)d_in[0];   // (8,1024,1536)
  const float* y   = (const float*)d_in[1];   // (8,16384,1024)
  const float* Wx  = (const float*)d_in[2];   // (768,1536)
  const float* bx  = (const float*)d_in[3];
  const float* Wy  = (const float*)d_in[4];   // (768,1024)
  const float* by  = (const float*)d_in[5];
  const float* ipw = (const float*)d_in[6];   // (2304,768)
  const float* ipb = (const float*)d_in[7];
  const float* Wo  = (const float*)d_in[8];   // (768,768)
  const float* ob  = (const float*)d_in[9];
  const float* lnw = (const float*)d_in[10];
  const float* lnb = (const float*)d_in[11];
  float* out = (float*)d_out;

  char* ws = (char*)d_ws;
  size_t off = 0;
  auto alloc = [&](size_t bytes) {
    void* p = ws + off;
    off += (bytes + 4095) & ~(size_t)4095;
    return p;
  };
  unsigned short* Wx_b  = (unsigned short*)alloc(768L * 1536 * 2);
  unsigned short* Wy_b  = (unsigned short*)alloc(768L * 1024 * 2);
  unsigned short* Wq_b  = (unsigned short*)alloc(768L * 768 * 2);
  unsigned short* WkT_b = (unsigned short*)alloc(768L * 768 * 2);
  unsigned short* Wv_b  = (unsigned short*)alloc(768L * 768 * 2);
  unsigned short* Wo_b  = (unsigned short*)alloc(768L * 768 * 2);
  float* ssx = (float*)alloc(8192L * 4);
  float* ssy = (float*)alloc(131072L * 4);
  unsigned short* z_b  = (unsigned short*)alloc(131072L * 768 * 2);
  unsigned short* xq_b = (unsigned short*)alloc(8192L * 768 * 2);
  char* reg = (char*)alloc(134217728L * 2);    // 256 MB scratch region
  unsigned short* q_b  = (unsigned short*)(reg + 25165824);       // 12.6 MB
  unsigned short* qk_b = (unsigned short*)(reg + 37748736);       // 151 MB (also u)
  unsigned short* o_b  = (unsigned short*)(reg + 188743680);      // 12.6 MB
  unsigned short* r_b  = (unsigned short*)(reg + 201326592);      // 12.6 MB (bf16)
  (void)ws_size; (void)in_sizes; (void)n_in; (void)out_size;

  // weights -> bf16 + zero ssx/ssy, one dispatch
  // items: 933888 vec4 + 589824 gather + 32768 ssy-f4 + 2048 ssx-f4 = 1558528
  wconv_kernel<<<6089, 256, 0, stream>>>(Wx, Wy, ipw, Wo,
                                         Wx_b, Wy_b, Wq_b, WkT_b, Wv_b, Wo_b,
                                         ssx, ssy);

  // merged dispatch: blocks [0,384) xq_raw = x@Wx^T+bx (long K, FIRST);
  //                  blocks [384,6528) z = y@Wy^T+by (XCD1D). Both + sumsq.
  gemm_af32_dual<<<6528, 256, 0, stream>>>(
      y, (const short*)Wy_b, z_b, by, ssy, 1024, 6, 6144,
      x, (const short*)Wx_b, xq_b, bx, ssx, 1536);

  // q = rs[m]*(xq_raw @ Wq^T) + bq   (rowscale folded into epilogue), BM=64
  gemm_bt<64, 128, EPI_BF16, false><<<dim3(128, 6, 1), 256, 0, stream>>>(
      (const short*)xq_b, (const short*)Wq_b, q_b, ipb, nullptr, nullptr, ssx,
      768, 768, 768, 768, 1.f, 0, 0, 0, 0, 0);

  // qk[m,h,:] = scale * q[m,h*64:+64] @ WkT[h]   (bk dropped: softmax-invariant)
  gemm_bt<128, 128, EPI_BF16, false><<<dim3(64, 6, 12), 256, 0, stream>>>(
      (const short*)q_b, (const short*)WkT_b, qk_b, nullptr, nullptr, nullptr, nullptr,
      768, 64, 9216, 64, 0.125f, 64, 49152, 768, 0, 0);

  // fused scores/softmax/u  (u overwrites qk slice per token)
  attn_kernel<<<8192, 256, 0, stream>>>(z_b, qk_b, ssy, qk_b);

  // o[:,h*64:+64] = u[:,h,:] @ Wv_h^T + bv_h
  gemm_bt<128, 64, EPI_BF16, false><<<dim3(64, 1, 12), 256, 0, stream>>>(
      (const short*)qk_b, (const short*)Wv_b, o_b, ipb + 1536, nullptr, nullptr, nullptr,
      9216, 768, 768, 768, 1.f, 768, 49152, 64, 64, 0);

  // r = o @ out_w^T + out_b + rs[m]*xq_raw   (bf16 residual out), BM=64
  gemm_bt<64, 128, EPI_BF16_RESID, false><<<dim3(128, 6, 1), 256, 0, stream>>>(
      (const short*)o_b, (const short*)Wo_b, r_b, ob, xq_b, nullptr, ssx,
      768, 768, 768, 768, 1.f, 0, 0, 0, 0, 0);

  // LayerNorm: 4 rows/block, wave-per-row, bf16 in / f32 out
  ln_kernel<<<2048, 256, 0, stream>>>(r_b, lnw, lnb, out);
}